// Round 6
// baseline (1036.692 us; speedup 1.0000x reference)
//
#include <hip/hip_runtime.h>
#include <cstddef>

// ---------------------------------------------------------------------------
// WaveletNet on MI355X — round 10: deep-lookahead K-pipeline (counted vmcnt).
// r9 post-mortem: reg-prefetch neutral -> within-phase ILP not the limit; the
// wall is the per-phase barrier draining vmcnt(0) with only 1 phase of load
// cover (< L3 latency + txn queue). Fix: 4 static buffers, stage 3 chunks
// ahead, each sub-step = {s_waitcnt vmcnt(8); s_barrier} (non-draining) ->
// stage(c+3) -> compute(c). Fully unrolled x4 -> all LDS indices static
// (r7's trap avoided). Same 64KB LDS, same swizzle. NT=2 path unchanged.
// ---------------------------------------------------------------------------

typedef unsigned short u16;
typedef unsigned int u32;
typedef __bf16 bf16x8 __attribute__((ext_vector_type(8)));
typedef float floatx4 __attribute__((ext_vector_type(4)));
typedef u16 u16x4 __attribute__((ext_vector_type(4)));
typedef u16 u16x8 __attribute__((ext_vector_type(8)));

__device__ __forceinline__ float b2f(u16 h) {
    union { u32 u; float f; } x; x.u = ((u32)h) << 16; return x.f;
}
__device__ __forceinline__ u16 f2b(float f) {
    union { float f; u32 u; } x; x.f = f;
    return (u16)((x.u + 0x7FFFu + ((x.u >> 16) & 1u)) >> 16);
}
__device__ __forceinline__ float lrelu_f(float v) { return v > 0.f ? v : 0.2f * v; }

// async global->LDS, 16B per lane; LDS dest = wave-uniform base + lane*16
__device__ __forceinline__ void gld16(const u16* g, u16* l) {
    __builtin_amdgcn_global_load_lds(
        (const __attribute__((address_space(1))) u32*)(const void*)g,
        (__attribute__((address_space(3))) u32*)(void*)l, 16, 0, 0);
}

#define WAITBAR(N) asm volatile("s_waitcnt vmcnt(" #N ")\ns_barrier" ::: "memory")

// ---------------- MFMA implicit-GEMM conv3x3, padded NHWC ----------------
// A[m][k], k = tap*Cin+ci; input padded [B][H+2][W+2][Cin], border zero.
// Wb = [Cout][9*Cin]. BM=128, BN=NT*32, BK=32. 4 waves 2x2.
// LDS swizzle: 16B slot within 64B row stored at slot ^ ((row>>1)&3), applied
// via pre-swizzled GLOBAL source (linear LDS dest) + swizzled ds_read.
// NT=4: 4 static buffers, 3-chunk lookahead, counted vmcnt(8) + light barrier
//       per chunk (never drains in main loop).
// NT=2: r5 two-buffer loop (one draining barrier / chunk).
template<int NT>
__global__ __launch_bounds__(256, 2)
void conv_mfma_k(const u16* __restrict__ in, int Cin, int iWp, int iImg,
                 const u16* __restrict__ wb, const float* __restrict__ bias,
                 const u16* __restrict__ skip, int sC, int sWp, int sImg, int spad,
                 u16* __restrict__ out, int Cst, int oWp, int oImg, int opad,
                 int logW, int logH)
{
    constexpr int BM = 128, BN = NT * 32;
    constexpr int ASZ = BM * 32;          // u16 per A buffer (4096 = 8 KB)
    constexpr int BSZ = BN * 32;
    constexpr int NBUF = (NT == 4) ? 4 : 2;
    __shared__ u16 At[NBUF * ASZ];        // 32 KB (NT=4) / 16 KB (NT=2)
    __shared__ u16 Bt[NBUF * BSZ];        // 32 KB (NT=4) /  8 KB (NT=2)

    const int tid = threadIdx.x;
    const int wid = tid >> 6, lane = tid & 63;
    const int W = 1 << logW, H = 1 << logH;
    const int mBase = blockIdx.x * BM;
    const int nBase = blockIdx.y * BN;
    const int K = 9 * Cin;
    const int kg = lane & 3;                      // 16B slot this lane stages
    const int rr = lane >> 2;                     // row-within-16 group
    const int kgs = kg ^ ((rr >> 1) & 3);         // inverse-swizzled k-slot

    // per-lane loop-invariant global base pointers (tap (-1,-1) == padded (py,px))
    const u16 *gA0, *gA1, *gB0, *gB1 = nullptr;
    {
        int m0 = mBase + wid * 32 + rr;
        int px0 = m0 & (W - 1), py0 = (m0 >> logW) & (H - 1), pb0 = m0 >> (logW + logH);
        gA0 = in + ((size_t)pb0 * iImg + (size_t)py0 * iWp + px0) * Cin + kgs * 8;
        int m1 = m0 + 16;
        int px1 = m1 & (W - 1), py1 = (m1 >> logW) & (H - 1), pb1 = m1 >> (logW + logH);
        gA1 = in + ((size_t)pb1 * iImg + (size_t)py1 * iWp + px1) * Cin + kgs * 8;
    }
    if constexpr (NT == 4) {
        gB0 = wb + (size_t)(nBase + wid * 32 + rr) * K + kgs * 8;
        gB1 = wb + (size_t)(nBase + wid * 32 + 16 + rr) * K + kgs * 8;
    } else {
        gB0 = wb + (size_t)(nBase + wid * 16 + rr) * K + kgs * 8;
    }
    u16* lA0 = &At[wid * 1024];
    u16* lA1 = &At[wid * 1024 + 512];
    u16* lB0 = (NT == 4) ? &Bt[wid * 1024] : &Bt[wid * 512];
    u16* lB1 = (NT == 4) ? &Bt[wid * 1024 + 512] : nullptr;

    const int wm = wid >> 1, wn = wid & 1;
    const int fm = lane & 15;
    // swizzled in-row u16 offset for ds_read (row bits 1..2 == fm bits 1..2)
    const int fk = ((lane >> 4) * 8) ^ (((fm >> 1) & 3) << 3);

    floatx4 acc[4][NT] = {};

    const int nChunks = K / 32;           // NT=4: 72/144/288 (mod 4 == 0)
    const size_t rowStep = (size_t)(iWp - 2) * Cin;
    int cbn = 0, tap = 0;

    auto stage = [&](int buf) {
        gld16(gA0, lA0 + buf * ASZ);
        gld16(gA1, lA1 + buf * ASZ);
        gld16(gB0, lB0 + buf * BSZ);
        if constexpr (NT == 4) gld16(gB1, lB1 + buf * BSZ);
        // uniform per-chunk pointer advance
        size_t dA = 32;
        cbn += 32;
        if (cbn == Cin) { cbn = 0; ++tap; dA = ((tap % 3 == 0) ? rowStep : (size_t)Cin) - (size_t)(Cin - 32); }
        gA0 += dA; gA1 += dA;
        gB0 += 32;
        if constexpr (NT == 4) gB1 += 32;
    };

    auto compute = [&](int buf) {
        const u16* Ab = &At[buf * ASZ];
        const u16* Bb = &Bt[buf * BSZ];
        bf16x8 af[4], bfr[NT];
#pragma unroll
        for (int mt = 0; mt < 4; ++mt)
            af[mt] = *(const bf16x8*)&Ab[(wm * 64 + mt * 16 + fm) * 32 + fk];
#pragma unroll
        for (int nt = 0; nt < NT; ++nt)
            bfr[nt] = *(const bf16x8*)&Bb[(wn * (NT * 16) + nt * 16 + fm) * 32 + fk];
        __builtin_amdgcn_s_setprio(1);
#pragma unroll
        for (int mt = 0; mt < 4; ++mt)
#pragma unroll
            for (int nt = 0; nt < NT; ++nt)
                acc[mt][nt] = __builtin_amdgcn_mfma_f32_16x16x32_bf16(af[mt], bfr[nt], acc[mt][nt], 0, 0, 0);
        __builtin_amdgcn_s_setprio(0);
    };

    if constexpr (NT == 4) {
        // deep pipeline: stage chunks 0,1,2 (12 loads in flight); each sub-step
        // waits ONLY the current chunk's 4 loads (vmcnt(8) keeps 8 in flight),
        // barrier (non-draining), stage chunk c+3, compute chunk c.
        stage(0); stage(1); stage(2);
        const int nIt = nChunks >> 2;
        for (int it = 0; it < nIt - 1; ++it) {
            WAITBAR(8); stage(3); compute(0);
            WAITBAR(8); stage(0); compute(1);
            WAITBAR(8); stage(1); compute(2);
            WAITBAR(8); stage(2); compute(3);
        }
        // tail iter: chunks n-4..n-1; only chunk n-1 still stages
        WAITBAR(8); stage(3); compute(0);
        WAITBAR(8); compute(1);
        WAITBAR(4); compute(2);
        WAITBAR(0); compute(3);
    } else {
        // r5 two-buffer loop: one draining barrier per chunk (nChunks 18/36)
        stage(0);
        __syncthreads();
        for (int kc = 0; kc < nChunks; kc += 2) {
            stage(1);
            compute(0);
            __syncthreads();
            if (kc + 2 < nChunks) stage(0);
            compute(1);
            __syncthreads();
        }
    }

    // epilogue: bias (+skip) + lrelu -> bf16 NHWC (padded or flat out)
    const int rq = (lane >> 4) * 4;
#pragma unroll
    for (int mt = 0; mt < 4; ++mt) {
        const int mrow = mBase + wm * 64 + mt * 16 + rq;
#pragma unroll
        for (int r = 0; r < 4; ++r) {
            int m2 = mrow + r;
            int px = m2 & (W - 1), py = (m2 >> logW) & (H - 1), pb2 = m2 >> (logW + logH);
            size_t ob = ((size_t)pb2 * oImg + (size_t)(py + opad) * oWp + (px + opad)) * Cst;
            size_t sb = 0;
            if (skip) sb = ((size_t)pb2 * sImg + (size_t)(py + spad) * sWp + (px + spad)) * sC;
#pragma unroll
            for (int nt = 0; nt < NT; ++nt) {
                int n = nBase + wn * (NT * 16) + nt * 16 + fm;
                float v = acc[mt][nt][r] + bias[n];
                if (skip) v += b2f(skip[sb + n]);
                v = lrelu_f(v);
                out[ob + n] = f2b(v);
            }
        }
    }
}

// ---------------- MFMA conv3x3, Cin=32 -> Cout=16 (convd2), padded in, flat out ----
__global__ __launch_bounds__(256)
void conv_n16_k(const u16* __restrict__ in, int iWp, int iImg,
                const u16* __restrict__ wb, const float* __restrict__ bias,
                u16* __restrict__ out, int logW, int logH)
{
    __shared__ u16 At[128 * 32];    // 8 KB
    __shared__ u16 Bt[16 * 32];     // 1 KB
    const int tid = threadIdx.x;
    const int wid = tid >> 6, lane = tid & 63;
    const int W = 1 << logW, H = 1 << logH;
    const int mBase = blockIdx.x * 128;
    const int kg = lane & 3, rr = lane >> 2;
    const int kgs = kg ^ ((rr >> 1) & 3);

    const u16 *gA0, *gA1;
    {
        int m0 = mBase + wid * 32 + rr;
        int px0 = m0 & (W - 1), py0 = (m0 >> logW) & (H - 1), pb0 = m0 >> (logW + logH);
        gA0 = in + ((size_t)pb0 * iImg + (size_t)py0 * iWp + px0) * 32 + kgs * 8;
        int m1 = m0 + 16;
        int px1 = m1 & (W - 1), py1 = (m1 >> logW) & (H - 1), pb1 = m1 >> (logW + logH);
        gA1 = in + ((size_t)pb1 * iImg + (size_t)py1 * iWp + px1) * 32 + kgs * 8;
    }
    const u16* gB = wb + (size_t)rr * 288 + kgs * 8;   // 16 rows (rr<16 used)
    u16* lA0 = &At[wid * 1024];
    u16* lA1 = &At[wid * 1024 + 512];

    const int fm = lane & 15;
    const int fk = ((lane >> 4) * 8) ^ (((fm >> 1) & 3) << 3);
    floatx4 acc[2] = {};
    const size_t rowStep = (size_t)(iWp - 2) * 32;

    for (int tap = 0; tap < 9; ++tap) {
        gld16(gA0, lA0);
        gld16(gA1, lA1);
        if (wid == 0) gld16(gB, &Bt[0]);
        __syncthreads();
        bf16x8 bf = *(const bf16x8*)&Bt[fm * 32 + fk];
#pragma unroll
        for (int mt = 0; mt < 2; ++mt) {
            bf16x8 af = *(const bf16x8*)&At[(wid * 32 + mt * 16 + fm) * 32 + fk];
            acc[mt] = __builtin_amdgcn_mfma_f32_16x16x32_bf16(af, bf, acc[mt], 0, 0, 0);
        }
        __syncthreads();
        size_t dA = (tap % 3 == 2) ? rowStep : (size_t)32;
        gA0 += dA; gA1 += dA; gB += 32;
    }

    const int rq = (lane >> 4) * 4;
    const float bn = bias[fm];
#pragma unroll
    for (int mt = 0; mt < 2; ++mt) {
#pragma unroll
        for (int r = 0; r < 4; ++r) {
            int m2 = mBase + wid * 32 + mt * 16 + rq + r;
            out[(size_t)m2 * 16 + fm] = f2b(lrelu_f(acc[mt][r] + bn));
        }
    }
}

// ---------------- direct NHWC conv3x3 (small channels), fp32 weights ----------------
template<int CIN, int COUT>
__global__ __launch_bounds__(256)
void conv_direct_k(const u16* __restrict__ in, int Sin,
                   const float* __restrict__ w, const float* __restrict__ bias,
                   u16* __restrict__ out, int Sout, int oWp, int oImg, int opad,
                   int logW, int logH, int total)
{
    int m = blockIdx.x * 256 + threadIdx.x;
    if (m >= total) return;
    const int W = 1 << logW, H = 1 << logH;
    const int px = m & (W - 1);
    const int py = (m >> logW) & (H - 1);
    const int pb = m >> (logW + logH);
    float acc[COUT];
#pragma unroll
    for (int o = 0; o < COUT; ++o) acc[o] = bias[o];
    for (int tap = 0; tap < 9; ++tap) {
        int dy = tap / 3 - 1, dx = tap % 3 - 1;
        int iy = py + dy, ix = px + dx;
        if ((unsigned)iy >= (unsigned)H || (unsigned)ix >= (unsigned)W) continue;
        const u16* p = in + (size_t)((((pb << logH) + iy) << logW) + ix) * Sin;
        if constexpr (CIN == 4) {
            u16x4 v = *(const u16x4*)p;
#pragma unroll
            for (int ci = 0; ci < 4; ++ci) {
                float f = b2f(v[ci]);
#pragma unroll
                for (int o = 0; o < COUT; ++o) acc[o] += f * w[(o * CIN + ci) * 9 + tap];
            }
        } else {
#pragma unroll
            for (int c8 = 0; c8 < CIN / 8; ++c8) {
                u16x8 v = *(const u16x8*)(p + c8 * 8);
#pragma unroll
                for (int j = 0; j < 8; ++j) {
                    int ci = c8 * 8 + j;
                    float f = b2f(v[j]);
#pragma unroll
                    for (int o = 0; o < COUT; ++o) acc[o] += f * w[(o * CIN + ci) * 9 + tap];
                }
            }
        }
    }
    size_t ob = ((size_t)pb * oImg + (size_t)(py + opad) * oWp + (px + opad)) * Sout;
#pragma unroll
    for (int o = 0; o < COUT; ++o)
        out[ob + o] = f2b(lrelu_f(acc[o]));
}

// ---------------- Haar wt / iwt, geometry-parametrized NHWC ----------------
__global__ __launch_bounds__(256)
void wt_in_k(const float* __restrict__ x, u16* __restrict__ out, int total)
{
    int idx = blockIdx.x * 256 + threadIdx.x;   // (b,h,w) of 8x256x256
    if (idx >= total) return;
    int wq = idx & 255, t = idx >> 8;
    int hq = t & 255, b = t >> 8;
    const float* p = x + ((size_t)b * 512 + 2 * hq) * 512 + 2 * wq;
    float a = p[0], bv = p[1], cv = p[512], d = p[513];
    u16x4 o = { f2b(0.25f * (a + bv + cv + d)),
                f2b(0.25f * (a + bv - cv - d) + 0.5f),
                f2b(0.25f * (a - bv + cv - d) + 0.5f),
                f2b(0.25f * (a - bv - cv + d) + 0.5f) };
    *(u16x4*)&out[(size_t)idx * 4] = o;
}

// in: maybe-padded NHWC [Sin]; out: maybe-padded NHWC [Sout], channels 4c+band
__global__ __launch_bounds__(256)
void wt_k(const u16* __restrict__ in, int Sin, int iWp, int iImg, int ipad,
          u16* __restrict__ out, int Sout, int oWp, int oImg, int opad,
          int logC, int logWo, int logHo, int total)
{
    int idx = blockIdx.x * 256 + threadIdx.x;
    if (idx >= total) return;
    const int C = 1 << logC, Wo = 1 << logWo, Ho = 1 << logHo;
    int c = idx & (C - 1); int t = idx >> logC;
    int wq = t & (Wo - 1); t >>= logWo;
    int hq = t & (Ho - 1); int b = t >> logHo;
    size_t p00 = ((size_t)b * iImg + (size_t)(2 * hq + ipad) * iWp + (2 * wq + ipad)) * Sin + c;
    float a  = b2f(in[p00]);
    float bv = b2f(in[p00 + Sin]);
    float cv = b2f(in[p00 + (size_t)iWp * Sin]);
    float d  = b2f(in[p00 + (size_t)iWp * Sin + Sin]);
    u16x4 o = { f2b(0.25f * (a + bv + cv + d)),
                f2b(0.25f * (a + bv - cv - d) + 0.5f),
                f2b(0.25f * (a - bv + cv - d) + 0.5f),
                f2b(0.25f * (a - bv - cv + d) + 0.5f) };
    *(u16x4*)&out[((size_t)b * oImg + (size_t)(hq + opad) * oWp + (wq + opad)) * Sout + 4 * c] = o;
}

// in: flat NHWC (unpadded), channels 4c+band; out: maybe-padded NHWC
__global__ __launch_bounds__(256)
void iwt_k(const u16* __restrict__ in, int Sin, int logC, int logW, int logH,
           u16* __restrict__ out, int Sout, int oWp, int oImg, int opad, int total)
{
    int idx = blockIdx.x * 256 + threadIdx.x;
    if (idx >= total) return;
    const int C = 1 << logC, W = 1 << logW;
    int c = idx & (C - 1); int t = idx >> logC;
    int wq = t & (W - 1); t >>= logW;
    int hq = t & ((1 << logH) - 1); int b = t >> logH;
    u16x4 v = *(const u16x4*)&in[(size_t)((((b << logH) + hq) << logW) + wq) * Sin + 4 * c];
    float y0 = b2f(v[0]);
    float y1 = 2.f * b2f(v[1]) - 1.f;
    float y2 = 2.f * b2f(v[2]) - 1.f;
    float y3 = 2.f * b2f(v[3]) - 1.f;
    float x00 = y0 + 0.5f * ( y1 + y2 + y3);
    float x01 = y0 + 0.5f * ( y1 - y2 - y3);
    float x10 = y0 + 0.5f * (-y1 + y2 - y3);
    float x11 = y0 + 0.5f * (-y1 - y2 + y3);
    size_t q = ((size_t)b * oImg + (size_t)(2 * hq + opad) * oWp + (2 * wq + opad)) * Sout + c;
    out[q] = f2b(x00);
    out[q + Sout] = f2b(x01);
    out[q + (size_t)oWp * Sout] = f2b(x10);
    out[q + (size_t)oWp * Sout + Sout] = f2b(x11);
}

__global__ __launch_bounds__(256)
void iwt_out_k(const u16* __restrict__ in, float* __restrict__ out, int total)
{
    int idx = blockIdx.x * 256 + threadIdx.x;   // (b,h,w) of 8x256x256
    if (idx >= total) return;
    int wq = idx & 255, t = idx >> 8;
    int hq = t & 255, b = t >> 8;
    u16x4 v = *(const u16x4*)&in[(size_t)idx * 4];
    float y0 = b2f(v[0]);
    float y1 = 2.f * b2f(v[1]) - 1.f;
    float y2 = 2.f * b2f(v[2]) - 1.f;
    float y3 = 2.f * b2f(v[3]) - 1.f;
    float x00 = y0 + 0.5f * ( y1 + y2 + y3);
    float x01 = y0 + 0.5f * ( y1 - y2 - y3);
    float x10 = y0 + 0.5f * (-y1 + y2 - y3);
    float x11 = y0 + 0.5f * (-y1 - y2 + y3);
    float* q = out + ((size_t)b * 512 + 2 * hq) * 512 + 2 * wq;
    q[0]   = 1.f / (1.f + __expf(-x00));
    q[1]   = 1.f / (1.f + __expf(-x01));
    q[512] = 1.f / (1.f + __expf(-x10));
    q[513] = 1.f / (1.f + __expf(-x11));
}

// ---------------- weight prep: [O][I][3][3] fp32 -> [O][tap][I] bf16 ----------------
__global__ __launch_bounds__(256)
void prep_w_k(const float* __restrict__ src, u16* __restrict__ dst, int logCIN, int total)
{
    int idx = blockIdx.x * 256 + threadIdx.x;
    if (idx >= total) return;
    const int CIN = 1 << logCIN;
    int ci = idx & (CIN - 1);
    int q = idx >> logCIN;
    int tap = q % 9, o = q / 9;
    dst[idx] = f2b(src[((size_t)(o * CIN + ci)) * 9 + tap]);
}

// ---------------- zero the 1-pixel border of a padded NHWC buffer ----------------
__global__ __launch_bounds__(256)
void zb_k(u16* __restrict__ buf, int Wp, int Hp, int C, int total)
{
    int idx = blockIdx.x * 256 + threadIdx.x;
    if (idx >= total) return;
    int c8 = idx % (C / 8); int t = idx / (C / 8);
    int nbp = 2 * Wp + 2 * (Hp - 2);
    int p = t % nbp; int b = t / nbp;
    int y, x;
    if (p < Wp) { y = 0; x = p; }
    else if (p < 2 * Wp) { y = Hp - 1; x = p - Wp; }
    else { int q = p - 2 * Wp; y = 1 + (q >> 1); x = (q & 1) ? Wp - 1 : 0; }
    u16x8 z = {0, 0, 0, 0, 0, 0, 0, 0};
    *(u16x8*)&buf[((size_t)b * Hp * Wp + (size_t)y * Wp + x) * C + c8 * 8] = z;
}

// ---------------------------------------------------------------------------
extern "C" void kernel_launch(void* const* d_in, const int* in_sizes, int n_in,
                              void* d_out, int out_size, void* d_ws, size_t ws_size,
                              hipStream_t stream)
{
    const float* x   = (const float*)d_in[0];
    const float* c1w = (const float*)d_in[1];  const float* c1b = (const float*)d_in[2];
    const float* c2w = (const float*)d_in[3];  const float* c2b = (const float*)d_in[4];
    const float* c3w = (const float*)d_in[5];  const float* c3b = (const float*)d_in[6];
    const float* c4w = (const float*)d_in[7];  const float* c4b = (const float*)d_in[8];
    const float* d1w = (const float*)d_in[9];  const float* d1b = (const float*)d_in[10];
    const float* d2w = (const float*)d_in[11]; const float* d2b = (const float*)d_in[12];
    const float* d3w = (const float*)d_in[13]; const float* d3b = (const float*)d_in[14];
    const float* d4w = (const float*)d_in[15]; const float* d4b = (const float*)d_in[16];

    const size_t MiB = 1u << 20;
    char* base = (char*)d_ws;
    // weights [0, 22 MiB)
    u16* c4wb = (u16*)base;                  // 9,437,184
    u16* c3wb = c4wb + 9437184;              //   589,824
    u16* d4wb = c3wb + 589824;               // 1,179,648
    u16* d3wb = d4wb + 1179648;              //    73,728
    u16* c2wb = d3wb + 73728;                //    36,864
    u16* d2wb = c2wb + 36864;                //     4,608
    // activations
    u16* CAT1p = (u16*)(base + 22  * MiB);   // [8,258,258,32]  padded: c1 | u2
    u16* CAT2p = (u16*)(base + 55  * MiB);   // [8,130,130,128] padded: c2 | u3
    u16* CAT3p = (u16*)(base + 88  * MiB);   // [8,66,66,512]   padded: c3 | u4
    u16* P1    = (u16*)(base + 123 * MiB);   // W2p -> W4p -> IC2
    u16* P2    = (u16*)(base + 142 * MiB);   // W3p -> C4p -> IC4 -> IC1
    u16* P3    = (u16*)(base + 161 * MiB);   // W1 -> C5p -> IC3 -> IW1
    float* outp = (float*)d_out;

    u16* W2p = P1; u16* W4p = P1; u16* IC2 = P1;
    u16* W3p = P2; u16* C4p = P2; u16* IC4 = P2; u16* IC1 = P2;
    u16* W1  = P3; u16* C5p = P3; u16* IC3 = P3; u16* IW1 = P3;

    auto cdiv = [](int a, int b) { return (a + b - 1) / b; };
    auto prep = [&](const float* s, u16* d, int logCIN, int total) {
        prep_w_k<<<cdiv(total, 256), 256, 0, stream>>>(s, d, logCIN, total);
    };
    auto zb = [&](u16* buf, int Wp, int Hp, int C) {
        int total = 8 * (2 * Wp + 2 * (Hp - 2)) * (C / 8);
        zb_k<<<cdiv(total, 256), 256, 0, stream>>>(buf, Wp, Hp, C, total);
    };
    auto mfma = [&](const u16* in, int Cin, int iWp, int iImg,
                    const u16* w, const float* bi,
                    const u16* skip, int sC, int sWp, int sImg, int spad,
                    int Cout, u16* out, int Cst, int oWp, int oImg, int opad,
                    int logW, int logH) {
        int M = 8 << (logW + logH);
        if (Cout % 128 == 0) {
            dim3 g(M / 128, Cout / 128);
            conv_mfma_k<4><<<g, 256, 0, stream>>>(in, Cin, iWp, iImg, w, bi,
                                                  skip, sC, sWp, sImg, spad,
                                                  out, Cst, oWp, oImg, opad, logW, logH);
        } else {
            dim3 g(M / 128, Cout / 64);
            conv_mfma_k<2><<<g, 256, 0, stream>>>(in, Cin, iWp, iImg, w, bi,
                                                  skip, sC, sWp, sImg, spad,
                                                  out, Cst, oWp, oImg, opad, logW, logH);
        }
    };

    // weight prep
    prep(c4w, c4wb, 10, 9437184);
    prep(c3w, c3wb, 8, 589824);
    prep(d4w, d4wb, 9, 1179648);
    prep(d3w, d3wb, 7, 73728);
    prep(c2w, c2wb, 6, 36864);
    prep(d2w, d2wb, 5, 4608);
    // borders whose slots have no earlier tenant
    zb(CAT1p, 258, 258, 32);
    zb(W2p, 130, 130, 64);
    zb(W3p, 66, 66, 256);
    zb(CAT2p, 130, 130, 128);
    zb(CAT3p, 66, 66, 512);

    const int P256 = 8 * 256 * 256;
    const int T2M = 2097152;   // 8*128*128*16 == 8*64*64*64 == 8*32*32*256
    const int I258 = 258 * 258;   // padded 256-image plane

    // w1 = wt(x) -> W1 (flat [8,256,256,4])
    wt_in_k<<<cdiv(P256, 256), 256, 0, stream>>>(x, W1, P256);
    // c1 -> CAT1p interior ch0..15 (direct, fp32 weights)
    conv_direct_k<4, 16><<<cdiv(P256, 256), 256, 0, stream>>>(
        W1, 4, c1w, c1b, CAT1p, 32, 258, I258, 1, 8, 8, P256);
    zb(C5p, 34, 34, 1024);                      // P3 free of W1 now
    // w2 = wt(c1) -> W2p padded [8,130,130,64]
    wt_k<<<cdiv(T2M, 256), 256, 0, stream>>>(CAT1p, 32, 258, I258, 1,
                                             W2p, 64, 130, 16900, 1, 4, 7, 7, T2M);
    // c2 -> CAT2p interior ch0..63
    mfma(W2p, 64, 130, 16900, c2wb, c2b, nullptr, 0, 0, 0, 0,
         64, CAT2p, 128, 130, 16900, 1, 7, 7);
    zb(W4p, 34, 34, 1024);                      // P1 free of W2p now
    // w3 = wt(c2) -> W3p padded [8,66,66,256]
    wt_k<<<cdiv(T2M, 256), 256, 0, stream>>>(CAT2p, 128, 130, 16900, 1,
                                             W3p, 256, 66, 4356, 1, 6, 6, 6, T2M);
    // c3 -> CAT3p interior ch0..255
    mfma(W3p, 256, 66, 4356, c3wb, c3b, nullptr, 0, 0, 0, 0,
         256, CAT3p, 512, 66, 4356, 1, 6, 6);
    zb(C4p, 34, 34, 1024);                      // P2 free of W3p now
    // w4 = wt(c3) -> W4p padded [8,34,34,1024]
    wt_k<<<cdiv(T2M, 256), 256, 0, stream>>>(CAT3p, 512, 66, 4356, 1,
                                             W4p, 1024, 34, 1156, 1, 8, 5, 5, T2M);
    // c4 -> C4p padded
    mfma(W4p, 1024, 34, 1156, c4wb, c4b, nullptr, 0, 0, 0, 0,
         1024, C4p, 1024, 34, 1156, 1, 5, 5);
    // c5 -> C5p padded
    mfma(C4p, 1024, 34, 1156, c4wb, c4b, nullptr, 0, 0, 0, 0,
         1024, C5p, 1024, 34, 1156, 1, 5, 5);
    // ic4 = lrelu(conv4(c5) + w4) -> IC4 flat [8,32,32,1024]
    mfma(C5p, 1024, 34, 1156, c4wb, c4b, W4p, 1024, 34, 1156, 1,
         1024, IC4, 1024, 32, 1024, 0, 5, 5);
    // u4 = iwt(ic4) -> CAT3p interior ch256..511
    iwt_k<<<cdiv(T2M, 256), 256, 0, stream>>>(IC4, 1024, 8, 5, 5,
                                              CAT3p + 256, 512, 66, 4356, 1, T2M);
    // ic3 = lrelu(convd4(cat3)) -> IC3 flat [8,64,64,256]
    mfma(CAT3p, 512, 66, 4356, d4wb, d4b, nullptr, 0, 0, 0, 0,
         256, IC3, 256, 64, 4096, 0, 6, 6);
    // u3 = iwt(ic3) -> CAT2p interior ch64..127
    iwt_k<<<cdiv(T2M, 256), 256, 0, stream>>>(IC3, 256, 6, 6, 6,
                                              CAT2p + 64, 128, 130, 16900, 1, T2M);
    // ic2 = lrelu(convd3(cat2)) -> IC2 flat [8,128,128,64]
    mfma(CAT2p, 128, 130, 16900, d3wb, d3b, nullptr, 0, 0, 0, 0,
         64, IC2, 64, 128, 16384, 0, 7, 7);
    // u2 = iwt(ic2) -> CAT1p interior ch16..31
    iwt_k<<<cdiv(T2M, 256), 256, 0, stream>>>(IC2, 64, 4, 7, 7,
                                              CAT1p + 16, 32, 258, I258, 1, T2M);
    // ic1 = lrelu(convd2(cat1)) -> IC1 flat [8,256,256,16]  (MFMA, N=16)
    conv_n16_k<<<dim3(P256 / 128), 256, 0, stream>>>(CAT1p, 258, I258, d2wb, d2b, IC1, 8, 8);
    // iw1 = lrelu(convd1(ic1)) -> IW1 flat [8,256,256,4]
    conv_direct_k<16, 4><<<cdiv(P256, 256), 256, 0, stream>>>(
        IC1, 16, d1w, d1b, IW1, 4, 256, 65536, 0, 8, 8, P256);
    // out = sigmoid(iwt(iw1))
    iwt_out_k<<<cdiv(P256, 256), 256, 0, stream>>>(IW1, outp, P256);
}

// Round 7
// 1008.503 us; speedup vs baseline: 1.0280x; 1.0280x over previous
//
#include <hip/hip_runtime.h>
#include <cstddef>

// ---------------------------------------------------------------------------
// WaveletNet on MI355X — round 11: in-block split-K (8-wave) for NT=4 layers.
// r10 post-mortem: counted-vmcnt deep pipe regressed (3rd failed hand-sched);
// base = r8 (183.8us conv4, 930us total). r8 wall: 766 cyc/chunk/CU vs ~570
// LDS floor; residual = barrier bubbles at only 2 waves/SIMD (grid-capped).
// Fix: 512-thread blocks; waves 0-3 / 4-7 each run an independent r5 2-buffer
// K-half pipeline in their own 32KB LDS half (64KB total, 2 blocks/CU -> 4
// waves/SIMD). Cross-half reduce via LDS at the end (no global partials).
// Same tiles/swizzle/traffic. NT=2 path unchanged.
// ---------------------------------------------------------------------------

typedef unsigned short u16;
typedef unsigned int u32;
typedef __bf16 bf16x8 __attribute__((ext_vector_type(8)));
typedef float floatx4 __attribute__((ext_vector_type(4)));
typedef u16 u16x4 __attribute__((ext_vector_type(4)));
typedef u16 u16x8 __attribute__((ext_vector_type(8)));

__device__ __forceinline__ float b2f(u16 h) {
    union { u32 u; float f; } x; x.u = ((u32)h) << 16; return x.f;
}
__device__ __forceinline__ u16 f2b(float f) {
    union { float f; u32 u; } x; x.f = f;
    return (u16)((x.u + 0x7FFFu + ((x.u >> 16) & 1u)) >> 16);
}
__device__ __forceinline__ float lrelu_f(float v) { return v > 0.f ? v : 0.2f * v; }

// async global->LDS, 16B per lane; LDS dest = wave-uniform base + lane*16
__device__ __forceinline__ void gld16(const u16* g, u16* l) {
    __builtin_amdgcn_global_load_lds(
        (const __attribute__((address_space(1))) u32*)(const void*)g,
        (__attribute__((address_space(3))) u32*)(void*)l, 16, 0, 0);
}

// ---------------- 8-wave split-K MFMA conv3x3 (Cout%128==0), padded NHWC ----
// BM=128, BN=128, BK=32. Waves 0-3 do K-half 0, waves 4-7 K-half 1; each half
// has its own 2-buffer pipeline in 32KB of LDS. Final cross-half reduce in
// LDS (lane-major float4 layout, conflict-free). Same XOR swizzle as before.
__global__ __launch_bounds__(512, 4)
void conv_mfma8_k(const u16* __restrict__ in, int Cin, int iWp, int iImg,
                  const u16* __restrict__ wb, const float* __restrict__ bias,
                  const u16* __restrict__ skip, int sC, int sWp, int sImg, int spad,
                  u16* __restrict__ out, int Cst, int oWp, int oImg, int opad,
                  int logW, int logH)
{
    __shared__ alignas(16) u16 S[32768];   // 64 KB; per half: A[2][4096] B[2][4096]

    const int tid = threadIdx.x;
    const int wid = tid >> 6, lane = tid & 63;
    const int half = wid >> 2, wl = wid & 3;
    const int W = 1 << logW, H = 1 << logH;
    const int mBase = blockIdx.x * 128;
    const int nBase = blockIdx.y * 128;
    const int K = 9 * Cin;
    const int nChunks = K / 32;
    const int nC = nChunks >> 1;          // chunks per half (144/72/36, even)

    const int kg = lane & 3;
    const int rr = lane >> 2;
    const int kgs = kg ^ ((rr >> 1) & 3); // inverse-swizzled k-slot

    // this half's starting chunk -> tap/cbn state
    const int k0 = half * nC * 32;
    int tap = k0 / Cin;
    int cbn = k0 - tap * Cin;

    // per-lane global base pointers at chunk k0
    const u16 *gA0, *gA1, *gB0, *gB1;
    {
        int ty = tap / 3, tx = tap - ty * 3;
        int m0 = mBase + wl * 32 + rr;
        int px0 = m0 & (W - 1), py0 = (m0 >> logW) & (H - 1), pb0 = m0 >> (logW + logH);
        gA0 = in + ((size_t)pb0 * iImg + (size_t)(py0 + ty) * iWp + (px0 + tx)) * Cin + cbn + kgs * 8;
        int m1 = m0 + 16;
        int px1 = m1 & (W - 1), py1 = (m1 >> logW) & (H - 1), pb1 = m1 >> (logW + logH);
        gA1 = in + ((size_t)pb1 * iImg + (size_t)(py1 + ty) * iWp + (px1 + tx)) * Cin + cbn + kgs * 8;
    }
    gB0 = wb + (size_t)(nBase + wl * 32 + rr) * K + k0 + kgs * 8;
    gB1 = wb + (size_t)(nBase + wl * 32 + 16 + rr) * K + k0 + kgs * 8;

    u16* Sb = &S[half * 16384];
    u16* lA0 = Sb + wl * 1024;            // + buf*4096
    u16* lA1 = Sb + wl * 1024 + 512;
    u16* lB0 = Sb + 8192 + wl * 1024;     // + buf*4096
    u16* lB1 = Sb + 8192 + wl * 1024 + 512;

    const int wm = wl >> 1, wn = wl & 1;
    const int fm = lane & 15;
    const int fk = ((lane >> 4) * 8) ^ (((fm >> 1) & 3) << 3);

    floatx4 acc[4][4] = {};

    const size_t rowStep = (size_t)(iWp - 2) * Cin;

    auto stage = [&](int buf) {
        gld16(gA0, lA0 + buf * 4096);
        gld16(gA1, lA1 + buf * 4096);
        gld16(gB0, lB0 + buf * 4096);
        gld16(gB1, lB1 + buf * 4096);
        size_t dA = 32;
        cbn += 32;
        if (cbn == Cin) { cbn = 0; ++tap; dA = ((tap % 3 == 0) ? rowStep : (size_t)Cin) - (size_t)(Cin - 32); }
        gA0 += dA; gA1 += dA;
        gB0 += 32; gB1 += 32;
    };

    auto compute = [&](int buf) {
        const u16* Ab = Sb + buf * 4096;
        const u16* Bb = Sb + 8192 + buf * 4096;
        bf16x8 af[4], bfr[4];
#pragma unroll
        for (int mt = 0; mt < 4; ++mt)
            af[mt] = *(const bf16x8*)&Ab[(wm * 64 + mt * 16 + fm) * 32 + fk];
#pragma unroll
        for (int nt = 0; nt < 4; ++nt)
            bfr[nt] = *(const bf16x8*)&Bb[(wn * 64 + nt * 16 + fm) * 32 + fk];
        __builtin_amdgcn_s_setprio(1);
#pragma unroll
        for (int mt = 0; mt < 4; ++mt)
#pragma unroll
            for (int nt = 0; nt < 4; ++nt)
                acc[mt][nt] = __builtin_amdgcn_mfma_f32_16x16x32_bf16(af[mt], bfr[nt], acc[mt][nt], 0, 0, 0);
        __builtin_amdgcn_s_setprio(0);
    };

    // per-half r5 2-buffer pipeline; all 8 waves share the barriers (same trip
    // count in both halves).
    stage(0);
    __syncthreads();
    for (int kc = 0; kc < nC; kc += 2) {
        stage(1);
        compute(0);
        __syncthreads();
        if (kc + 2 < nC) stage(0);
        compute(1);
        __syncthreads();
    }

    // cross-half reduce: upper half writes acc to LDS (lane-major float4 ->
    // conflict-free), lower half adds. K-loop ended with a barrier, so S free.
    float* R = (float*)S;
    if (half == 1) {
#pragma unroll
        for (int mt = 0; mt < 4; ++mt)
#pragma unroll
            for (int nt = 0; nt < 4; ++nt) {
                int j = mt * 4 + nt;
                *(floatx4*)&R[(size_t)(((wl * 16 + j) * 64) + lane) * 4] = acc[mt][nt];
            }
    }
    __syncthreads();
    if (half == 0) {
        const int rq = (lane >> 4) * 4;
#pragma unroll
        for (int mt = 0; mt < 4; ++mt)
#pragma unroll
            for (int nt = 0; nt < 4; ++nt) {
                int j = mt * 4 + nt;
                floatx4 v = *(const floatx4*)&R[(size_t)(((wl * 16 + j) * 64) + lane) * 4];
                acc[mt][nt] = acc[mt][nt] + v;
            }
        // epilogue: bias (+skip) + lrelu -> bf16 NHWC (padded or flat out)
#pragma unroll
        for (int mt = 0; mt < 4; ++mt) {
            const int mrow = mBase + wm * 64 + mt * 16 + rq;
#pragma unroll
            for (int r = 0; r < 4; ++r) {
                int m2 = mrow + r;
                int px = m2 & (W - 1), py = (m2 >> logW) & (H - 1), pb2 = m2 >> (logW + logH);
                size_t ob = ((size_t)pb2 * oImg + (size_t)(py + opad) * oWp + (px + opad)) * Cst;
                size_t sb = 0;
                if (skip) sb = ((size_t)pb2 * sImg + (size_t)(py + spad) * sWp + (px + spad)) * sC;
#pragma unroll
                for (int nt = 0; nt < 4; ++nt) {
                    int n = nBase + wn * 64 + nt * 16 + fm;
                    float v = acc[mt][nt][r] + bias[n];
                    if (skip) v += b2f(skip[sb + n]);
                    v = lrelu_f(v);
                    out[ob + n] = f2b(v);
                }
            }
        }
    }
}

// ---------------- 4-wave MFMA conv3x3 (NT=2: Cout=64), padded NHWC ----------
// r5/r8 structure: 2 buffers, one draining barrier per chunk.
__global__ __launch_bounds__(256)
void conv_mfma_k(const u16* __restrict__ in, int Cin, int iWp, int iImg,
                 const u16* __restrict__ wb, const float* __restrict__ bias,
                 const u16* __restrict__ skip, int sC, int sWp, int sImg, int spad,
                 u16* __restrict__ out, int Cst, int oWp, int oImg, int opad,
                 int logW, int logH)
{
    constexpr int NT = 2;
    constexpr int BM = 128, BN = NT * 32;
    constexpr int ASZ = BM * 32;
    constexpr int BSZ = BN * 32;
    __shared__ u16 At[2 * ASZ];           // 16 KB
    __shared__ u16 Bt[2 * BSZ];           // 8 KB

    const int tid = threadIdx.x;
    const int wid = tid >> 6, lane = tid & 63;
    const int W = 1 << logW, H = 1 << logH;
    const int mBase = blockIdx.x * BM;
    const int nBase = blockIdx.y * BN;
    const int K = 9 * Cin;
    const int kg = lane & 3;
    const int rr = lane >> 2;
    const int kgs = kg ^ ((rr >> 1) & 3);

    const u16 *gA0, *gA1, *gB0;
    {
        int m0 = mBase + wid * 32 + rr;
        int px0 = m0 & (W - 1), py0 = (m0 >> logW) & (H - 1), pb0 = m0 >> (logW + logH);
        gA0 = in + ((size_t)pb0 * iImg + (size_t)py0 * iWp + px0) * Cin + kgs * 8;
        int m1 = m0 + 16;
        int px1 = m1 & (W - 1), py1 = (m1 >> logW) & (H - 1), pb1 = m1 >> (logW + logH);
        gA1 = in + ((size_t)pb1 * iImg + (size_t)py1 * iWp + px1) * Cin + kgs * 8;
    }
    gB0 = wb + (size_t)(nBase + wid * 16 + rr) * K + kgs * 8;
    u16* lA0 = &At[wid * 1024];
    u16* lA1 = &At[wid * 1024 + 512];
    u16* lB0 = &Bt[wid * 512];

    const int wm = wid >> 1, wn = wid & 1;
    const int fm = lane & 15;
    const int fk = ((lane >> 4) * 8) ^ (((fm >> 1) & 3) << 3);

    floatx4 acc[4][NT] = {};

    const int nChunks = K / 32;
    const size_t rowStep = (size_t)(iWp - 2) * Cin;
    int cbn = 0, tap = 0;

    auto stage = [&](int buf) {
        gld16(gA0, lA0 + buf * ASZ);
        gld16(gA1, lA1 + buf * ASZ);
        gld16(gB0, lB0 + buf * BSZ);
        size_t dA = 32;
        cbn += 32;
        if (cbn == Cin) { cbn = 0; ++tap; dA = ((tap % 3 == 0) ? rowStep : (size_t)Cin) - (size_t)(Cin - 32); }
        gA0 += dA; gA1 += dA;
        gB0 += 32;
    };

    auto compute = [&](int buf) {
        const u16* Ab = &At[buf * ASZ];
        const u16* Bb = &Bt[buf * BSZ];
        bf16x8 af[4], bfr[NT];
#pragma unroll
        for (int mt = 0; mt < 4; ++mt)
            af[mt] = *(const bf16x8*)&Ab[(wm * 64 + mt * 16 + fm) * 32 + fk];
#pragma unroll
        for (int nt = 0; nt < NT; ++nt)
            bfr[nt] = *(const bf16x8*)&Bb[(wn * (NT * 16) + nt * 16 + fm) * 32 + fk];
        __builtin_amdgcn_s_setprio(1);
#pragma unroll
        for (int mt = 0; mt < 4; ++mt)
#pragma unroll
            for (int nt = 0; nt < NT; ++nt)
                acc[mt][nt] = __builtin_amdgcn_mfma_f32_16x16x32_bf16(af[mt], bfr[nt], acc[mt][nt], 0, 0, 0);
        __builtin_amdgcn_s_setprio(0);
    };

    stage(0);
    __syncthreads();
    for (int kc = 0; kc < nChunks; kc += 2) {
        stage(1);
        compute(0);
        __syncthreads();
        if (kc + 2 < nChunks) stage(0);
        compute(1);
        __syncthreads();
    }

    const int rq = (lane >> 4) * 4;
#pragma unroll
    for (int mt = 0; mt < 4; ++mt) {
        const int mrow = mBase + wm * 64 + mt * 16 + rq;
#pragma unroll
        for (int r = 0; r < 4; ++r) {
            int m2 = mrow + r;
            int px = m2 & (W - 1), py = (m2 >> logW) & (H - 1), pb2 = m2 >> (logW + logH);
            size_t ob = ((size_t)pb2 * oImg + (size_t)(py + opad) * oWp + (px + opad)) * Cst;
            size_t sb = 0;
            if (skip) sb = ((size_t)pb2 * sImg + (size_t)(py + spad) * sWp + (px + spad)) * sC;
#pragma unroll
            for (int nt = 0; nt < NT; ++nt) {
                int n = nBase + wn * (NT * 16) + nt * 16 + fm;
                float v = acc[mt][nt][r] + bias[n];
                if (skip) v += b2f(skip[sb + n]);
                v = lrelu_f(v);
                out[ob + n] = f2b(v);
            }
        }
    }
}

// ---------------- MFMA conv3x3, Cin=32 -> Cout=16 (convd2), padded in, flat out ----
__global__ __launch_bounds__(256)
void conv_n16_k(const u16* __restrict__ in, int iWp, int iImg,
                const u16* __restrict__ wb, const float* __restrict__ bias,
                u16* __restrict__ out, int logW, int logH)
{
    __shared__ u16 At[128 * 32];    // 8 KB
    __shared__ u16 Bt[16 * 32];     // 1 KB
    const int tid = threadIdx.x;
    const int wid = tid >> 6, lane = tid & 63;
    const int W = 1 << logW, H = 1 << logH;
    const int mBase = blockIdx.x * 128;
    const int kg = lane & 3, rr = lane >> 2;
    const int kgs = kg ^ ((rr >> 1) & 3);

    const u16 *gA0, *gA1;
    {
        int m0 = mBase + wid * 32 + rr;
        int px0 = m0 & (W - 1), py0 = (m0 >> logW) & (H - 1), pb0 = m0 >> (logW + logH);
        gA0 = in + ((size_t)pb0 * iImg + (size_t)py0 * iWp + px0) * 32 + kgs * 8;
        int m1 = m0 + 16;
        int px1 = m1 & (W - 1), py1 = (m1 >> logW) & (H - 1), pb1 = m1 >> (logW + logH);
        gA1 = in + ((size_t)pb1 * iImg + (size_t)py1 * iWp + px1) * 32 + kgs * 8;
    }
    const u16* gB = wb + (size_t)rr * 288 + kgs * 8;   // 16 rows (rr<16 used)
    u16* lA0 = &At[wid * 1024];
    u16* lA1 = &At[wid * 1024 + 512];

    const int fm = lane & 15;
    const int fk = ((lane >> 4) * 8) ^ (((fm >> 1) & 3) << 3);
    floatx4 acc[2] = {};
    const size_t rowStep = (size_t)(iWp - 2) * 32;

    for (int tap = 0; tap < 9; ++tap) {
        gld16(gA0, lA0);
        gld16(gA1, lA1);
        if (wid == 0) gld16(gB, &Bt[0]);
        __syncthreads();
        bf16x8 bf = *(const bf16x8*)&Bt[fm * 32 + fk];
#pragma unroll
        for (int mt = 0; mt < 2; ++mt) {
            bf16x8 af = *(const bf16x8*)&At[(wid * 32 + mt * 16 + fm) * 32 + fk];
            acc[mt] = __builtin_amdgcn_mfma_f32_16x16x32_bf16(af, bf, acc[mt], 0, 0, 0);
        }
        __syncthreads();
        size_t dA = (tap % 3 == 2) ? rowStep : (size_t)32;
        gA0 += dA; gA1 += dA; gB += 32;
    }

    const int rq = (lane >> 4) * 4;
    const float bn = bias[fm];
#pragma unroll
    for (int mt = 0; mt < 2; ++mt) {
#pragma unroll
        for (int r = 0; r < 4; ++r) {
            int m2 = mBase + wid * 32 + mt * 16 + rq + r;
            out[(size_t)m2 * 16 + fm] = f2b(lrelu_f(acc[mt][r] + bn));
        }
    }
}

// ---------------- direct NHWC conv3x3 (small channels), fp32 weights ----------------
template<int CIN, int COUT>
__global__ __launch_bounds__(256)
void conv_direct_k(const u16* __restrict__ in, int Sin,
                   const float* __restrict__ w, const float* __restrict__ bias,
                   u16* __restrict__ out, int Sout, int oWp, int oImg, int opad,
                   int logW, int logH, int total)
{
    int m = blockIdx.x * 256 + threadIdx.x;
    if (m >= total) return;
    const int W = 1 << logW, H = 1 << logH;
    const int px = m & (W - 1);
    const int py = (m >> logW) & (H - 1);
    const int pb = m >> (logW + logH);
    float acc[COUT];
#pragma unroll
    for (int o = 0; o < COUT; ++o) acc[o] = bias[o];
    for (int tap = 0; tap < 9; ++tap) {
        int dy = tap / 3 - 1, dx = tap % 3 - 1;
        int iy = py + dy, ix = px + dx;
        if ((unsigned)iy >= (unsigned)H || (unsigned)ix >= (unsigned)W) continue;
        const u16* p = in + (size_t)((((pb << logH) + iy) << logW) + ix) * Sin;
        if constexpr (CIN == 4) {
            u16x4 v = *(const u16x4*)p;
#pragma unroll
            for (int ci = 0; ci < 4; ++ci) {
                float f = b2f(v[ci]);
#pragma unroll
                for (int o = 0; o < COUT; ++o) acc[o] += f * w[(o * CIN + ci) * 9 + tap];
            }
        } else {
#pragma unroll
            for (int c8 = 0; c8 < CIN / 8; ++c8) {
                u16x8 v = *(const u16x8*)(p + c8 * 8);
#pragma unroll
                for (int j = 0; j < 8; ++j) {
                    int ci = c8 * 8 + j;
                    float f = b2f(v[j]);
#pragma unroll
                    for (int o = 0; o < COUT; ++o) acc[o] += f * w[(o * CIN + ci) * 9 + tap];
                }
            }
        }
    }
    size_t ob = ((size_t)pb * oImg + (size_t)(py + opad) * oWp + (px + opad)) * Sout;
#pragma unroll
    for (int o = 0; o < COUT; ++o)
        out[ob + o] = f2b(lrelu_f(acc[o]));
}

// ---------------- Haar wt / iwt, geometry-parametrized NHWC ----------------
__global__ __launch_bounds__(256)
void wt_in_k(const float* __restrict__ x, u16* __restrict__ out, int total)
{
    int idx = blockIdx.x * 256 + threadIdx.x;   // (b,h,w) of 8x256x256
    if (idx >= total) return;
    int wq = idx & 255, t = idx >> 8;
    int hq = t & 255, b = t >> 8;
    const float* p = x + ((size_t)b * 512 + 2 * hq) * 512 + 2 * wq;
    float a = p[0], bv = p[1], cv = p[512], d = p[513];
    u16x4 o = { f2b(0.25f * (a + bv + cv + d)),
                f2b(0.25f * (a + bv - cv - d) + 0.5f),
                f2b(0.25f * (a - bv + cv - d) + 0.5f),
                f2b(0.25f * (a - bv - cv + d) + 0.5f) };
    *(u16x4*)&out[(size_t)idx * 4] = o;
}

// in: maybe-padded NHWC [Sin]; out: maybe-padded NHWC [Sout], channels 4c+band
__global__ __launch_bounds__(256)
void wt_k(const u16* __restrict__ in, int Sin, int iWp, int iImg, int ipad,
          u16* __restrict__ out, int Sout, int oWp, int oImg, int opad,
          int logC, int logWo, int logHo, int total)
{
    int idx = blockIdx.x * 256 + threadIdx.x;
    if (idx >= total) return;
    const int C = 1 << logC, Wo = 1 << logWo, Ho = 1 << logHo;
    int c = idx & (C - 1); int t = idx >> logC;
    int wq = t & (Wo - 1); t >>= logWo;
    int hq = t & (Ho - 1); int b = t >> logHo;
    size_t p00 = ((size_t)b * iImg + (size_t)(2 * hq + ipad) * iWp + (2 * wq + ipad)) * Sin + c;
    float a  = b2f(in[p00]);
    float bv = b2f(in[p00 + Sin]);
    float cv = b2f(in[p00 + (size_t)iWp * Sin]);
    float d  = b2f(in[p00 + (size_t)iWp * Sin + Sin]);
    u16x4 o = { f2b(0.25f * (a + bv + cv + d)),
                f2b(0.25f * (a + bv - cv - d) + 0.5f),
                f2b(0.25f * (a - bv + cv - d) + 0.5f),
                f2b(0.25f * (a - bv - cv + d) + 0.5f) };
    *(u16x4*)&out[((size_t)b * oImg + (size_t)(hq + opad) * oWp + (wq + opad)) * Sout + 4 * c] = o;
}

// in: flat NHWC (unpadded), channels 4c+band; out: maybe-padded NHWC
__global__ __launch_bounds__(256)
void iwt_k(const u16* __restrict__ in, int Sin, int logC, int logW, int logH,
           u16* __restrict__ out, int Sout, int oWp, int oImg, int opad, int total)
{
    int idx = blockIdx.x * 256 + threadIdx.x;
    if (idx >= total) return;
    const int C = 1 << logC, W = 1 << logW;
    int c = idx & (C - 1); int t = idx >> logC;
    int wq = t & (W - 1); t >>= logW;
    int hq = t & ((1 << logH) - 1); int b = t >> logH;
    u16x4 v = *(const u16x4*)&in[(size_t)((((b << logH) + hq) << logW) + wq) * Sin + 4 * c];
    float y0 = b2f(v[0]);
    float y1 = 2.f * b2f(v[1]) - 1.f;
    float y2 = 2.f * b2f(v[2]) - 1.f;
    float y3 = 2.f * b2f(v[3]) - 1.f;
    float x00 = y0 + 0.5f * ( y1 + y2 + y3);
    float x01 = y0 + 0.5f * ( y1 - y2 - y3);
    float x10 = y0 + 0.5f * (-y1 + y2 - y3);
    float x11 = y0 + 0.5f * (-y1 - y2 + y3);
    size_t q = ((size_t)b * oImg + (size_t)(2 * hq + opad) * oWp + (2 * wq + opad)) * Sout + c;
    out[q] = f2b(x00);
    out[q + Sout] = f2b(x01);
    out[q + (size_t)oWp * Sout] = f2b(x10);
    out[q + (size_t)oWp * Sout + Sout] = f2b(x11);
}

__global__ __launch_bounds__(256)
void iwt_out_k(const u16* __restrict__ in, float* __restrict__ out, int total)
{
    int idx = blockIdx.x * 256 + threadIdx.x;   // (b,h,w) of 8x256x256
    if (idx >= total) return;
    int wq = idx & 255, t = idx >> 8;
    int hq = t & 255, b = t >> 8;
    u16x4 v = *(const u16x4*)&in[(size_t)idx * 4];
    float y0 = b2f(v[0]);
    float y1 = 2.f * b2f(v[1]) - 1.f;
    float y2 = 2.f * b2f(v[2]) - 1.f;
    float y3 = 2.f * b2f(v[3]) - 1.f;
    float x00 = y0 + 0.5f * ( y1 + y2 + y3);
    float x01 = y0 + 0.5f * ( y1 - y2 - y3);
    float x10 = y0 + 0.5f * (-y1 + y2 - y3);
    float x11 = y0 + 0.5f * (-y1 - y2 + y3);
    float* q = out + ((size_t)b * 512 + 2 * hq) * 512 + 2 * wq;
    q[0]   = 1.f / (1.f + __expf(-x00));
    q[1]   = 1.f / (1.f + __expf(-x01));
    q[512] = 1.f / (1.f + __expf(-x10));
    q[513] = 1.f / (1.f + __expf(-x11));
}

// ---------------- weight prep: [O][I][3][3] fp32 -> [O][tap][I] bf16 ----------------
__global__ __launch_bounds__(256)
void prep_w_k(const float* __restrict__ src, u16* __restrict__ dst, int logCIN, int total)
{
    int idx = blockIdx.x * 256 + threadIdx.x;
    if (idx >= total) return;
    const int CIN = 1 << logCIN;
    int ci = idx & (CIN - 1);
    int q = idx >> logCIN;
    int tap = q % 9, o = q / 9;
    dst[idx] = f2b(src[((size_t)(o * CIN + ci)) * 9 + tap]);
}

// ---------------- zero the 1-pixel border of a padded NHWC buffer ----------------
__global__ __launch_bounds__(256)
void zb_k(u16* __restrict__ buf, int Wp, int Hp, int C, int total)
{
    int idx = blockIdx.x * 256 + threadIdx.x;
    if (idx >= total) return;
    int c8 = idx % (C / 8); int t = idx / (C / 8);
    int nbp = 2 * Wp + 2 * (Hp - 2);
    int p = t % nbp; int b = t / nbp;
    int y, x;
    if (p < Wp) { y = 0; x = p; }
    else if (p < 2 * Wp) { y = Hp - 1; x = p - Wp; }
    else { int q = p - 2 * Wp; y = 1 + (q >> 1); x = (q & 1) ? Wp - 1 : 0; }
    u16x8 z = {0, 0, 0, 0, 0, 0, 0, 0};
    *(u16x8*)&buf[((size_t)b * Hp * Wp + (size_t)y * Wp + x) * C + c8 * 8] = z;
}

// ---------------------------------------------------------------------------
extern "C" void kernel_launch(void* const* d_in, const int* in_sizes, int n_in,
                              void* d_out, int out_size, void* d_ws, size_t ws_size,
                              hipStream_t stream)
{
    const float* x   = (const float*)d_in[0];
    const float* c1w = (const float*)d_in[1];  const float* c1b = (const float*)d_in[2];
    const float* c2w = (const float*)d_in[3];  const float* c2b = (const float*)d_in[4];
    const float* c3w = (const float*)d_in[5];  const float* c3b = (const float*)d_in[6];
    const float* c4w = (const float*)d_in[7];  const float* c4b = (const float*)d_in[8];
    const float* d1w = (const float*)d_in[9];  const float* d1b = (const float*)d_in[10];
    const float* d2w = (const float*)d_in[11]; const float* d2b = (const float*)d_in[12];
    const float* d3w = (const float*)d_in[13]; const float* d3b = (const float*)d_in[14];
    const float* d4w = (const float*)d_in[15]; const float* d4b = (const float*)d_in[16];

    const size_t MiB = 1u << 20;
    char* base = (char*)d_ws;
    // weights [0, 22 MiB)
    u16* c4wb = (u16*)base;                  // 9,437,184
    u16* c3wb = c4wb + 9437184;              //   589,824
    u16* d4wb = c3wb + 589824;               // 1,179,648
    u16* d3wb = d4wb + 1179648;              //    73,728
    u16* c2wb = d3wb + 73728;                //    36,864
    u16* d2wb = c2wb + 36864;                //     4,608
    // activations
    u16* CAT1p = (u16*)(base + 22  * MiB);   // [8,258,258,32]  padded: c1 | u2
    u16* CAT2p = (u16*)(base + 55  * MiB);   // [8,130,130,128] padded: c2 | u3
    u16* CAT3p = (u16*)(base + 88  * MiB);   // [8,66,66,512]   padded: c3 | u4
    u16* P1    = (u16*)(base + 123 * MiB);   // W2p -> W4p -> IC2
    u16* P2    = (u16*)(base + 142 * MiB);   // W3p -> C4p -> IC4 -> IC1
    u16* P3    = (u16*)(base + 161 * MiB);   // W1 -> C5p -> IC3 -> IW1
    float* outp = (float*)d_out;

    u16* W2p = P1; u16* W4p = P1; u16* IC2 = P1;
    u16* W3p = P2; u16* C4p = P2; u16* IC4 = P2; u16* IC1 = P2;
    u16* W1  = P3; u16* C5p = P3; u16* IC3 = P3; u16* IW1 = P3;

    auto cdiv = [](int a, int b) { return (a + b - 1) / b; };
    auto prep = [&](const float* s, u16* d, int logCIN, int total) {
        prep_w_k<<<cdiv(total, 256), 256, 0, stream>>>(s, d, logCIN, total);
    };
    auto zb = [&](u16* buf, int Wp, int Hp, int C) {
        int total = 8 * (2 * Wp + 2 * (Hp - 2)) * (C / 8);
        zb_k<<<cdiv(total, 256), 256, 0, stream>>>(buf, Wp, Hp, C, total);
    };
    auto mfma = [&](const u16* in, int Cin, int iWp, int iImg,
                    const u16* w, const float* bi,
                    const u16* skip, int sC, int sWp, int sImg, int spad,
                    int Cout, u16* out, int Cst, int oWp, int oImg, int opad,
                    int logW, int logH) {
        int M = 8 << (logW + logH);
        if (Cout % 128 == 0) {
            dim3 g(M / 128, Cout / 128);
            conv_mfma8_k<<<g, 512, 0, stream>>>(in, Cin, iWp, iImg, w, bi,
                                                skip, sC, sWp, sImg, spad,
                                                out, Cst, oWp, oImg, opad, logW, logH);
        } else {
            dim3 g(M / 128, Cout / 64);
            conv_mfma_k<<<g, 256, 0, stream>>>(in, Cin, iWp, iImg, w, bi,
                                               skip, sC, sWp, sImg, spad,
                                               out, Cst, oWp, oImg, opad, logW, logH);
        }
    };

    // weight prep
    prep(c4w, c4wb, 10, 9437184);
    prep(c3w, c3wb, 8, 589824);
    prep(d4w, d4wb, 9, 1179648);
    prep(d3w, d3wb, 7, 73728);
    prep(c2w, c2wb, 6, 36864);
    prep(d2w, d2wb, 5, 4608);
    // borders whose slots have no earlier tenant
    zb(CAT1p, 258, 258, 32);
    zb(W2p, 130, 130, 64);
    zb(W3p, 66, 66, 256);
    zb(CAT2p, 130, 130, 128);
    zb(CAT3p, 66, 66, 512);

    const int P256 = 8 * 256 * 256;
    const int T2M = 2097152;   // 8*128*128*16 == 8*64*64*64 == 8*32*32*256
    const int I258 = 258 * 258;   // padded 256-image plane

    // w1 = wt(x) -> W1 (flat [8,256,256,4])
    wt_in_k<<<cdiv(P256, 256), 256, 0, stream>>>(x, W1, P256);
    // c1 -> CAT1p interior ch0..15 (direct, fp32 weights)
    conv_direct_k<4, 16><<<cdiv(P256, 256), 256, 0, stream>>>(
        W1, 4, c1w, c1b, CAT1p, 32, 258, I258, 1, 8, 8, P256);
    zb(C5p, 34, 34, 1024);                      // P3 free of W1 now
    // w2 = wt(c1) -> W2p padded [8,130,130,64]
    wt_k<<<cdiv(T2M, 256), 256, 0, stream>>>(CAT1p, 32, 258, I258, 1,
                                             W2p, 64, 130, 16900, 1, 4, 7, 7, T2M);
    // c2 -> CAT2p interior ch0..63
    mfma(W2p, 64, 130, 16900, c2wb, c2b, nullptr, 0, 0, 0, 0,
         64, CAT2p, 128, 130, 16900, 1, 7, 7);
    zb(W4p, 34, 34, 1024);                      // P1 free of W2p now
    // w3 = wt(c2) -> W3p padded [8,66,66,256]
    wt_k<<<cdiv(T2M, 256), 256, 0, stream>>>(CAT2p, 128, 130, 16900, 1,
                                             W3p, 256, 66, 4356, 1, 6, 6, 6, T2M);
    // c3 -> CAT3p interior ch0..255
    mfma(W3p, 256, 66, 4356, c3wb, c3b, nullptr, 0, 0, 0, 0,
         256, CAT3p, 512, 66, 4356, 1, 6, 6);
    zb(C4p, 34, 34, 1024);                      // P2 free of W3p now
    // w4 = wt(c3) -> W4p padded [8,34,34,1024]
    wt_k<<<cdiv(T2M, 256), 256, 0, stream>>>(CAT3p, 512, 66, 4356, 1,
                                             W4p, 1024, 34, 1156, 1, 8, 5, 5, T2M);
    // c4 -> C4p padded
    mfma(W4p, 1024, 34, 1156, c4wb, c4b, nullptr, 0, 0, 0, 0,
         1024, C4p, 1024, 34, 1156, 1, 5, 5);
    // c5 -> C5p padded
    mfma(C4p, 1024, 34, 1156, c4wb, c4b, nullptr, 0, 0, 0, 0,
         1024, C5p, 1024, 34, 1156, 1, 5, 5);
    // ic4 = lrelu(conv4(c5) + w4) -> IC4 flat [8,32,32,1024]
    mfma(C5p, 1024, 34, 1156, c4wb, c4b, W4p, 1024, 34, 1156, 1,
         1024, IC4, 1024, 32, 1024, 0, 5, 5);
    // u4 = iwt(ic4) -> CAT3p interior ch256..511
    iwt_k<<<cdiv(T2M, 256), 256, 0, stream>>>(IC4, 1024, 8, 5, 5,
                                              CAT3p + 256, 512, 66, 4356, 1, T2M);
    // ic3 = lrelu(convd4(cat3)) -> IC3 flat [8,64,64,256]
    mfma(CAT3p, 512, 66, 4356, d4wb, d4b, nullptr, 0, 0, 0, 0,
         256, IC3, 256, 64, 4096, 0, 6, 6);
    // u3 = iwt(ic3) -> CAT2p interior ch64..127
    iwt_k<<<cdiv(T2M, 256), 256, 0, stream>>>(IC3, 256, 6, 6, 6,
                                              CAT2p + 64, 128, 130, 16900, 1, T2M);
    // ic2 = lrelu(convd3(cat2)) -> IC2 flat [8,128,128,64]
    mfma(CAT2p, 128, 130, 16900, d3wb, d3b, nullptr, 0, 0, 0, 0,
         64, IC2, 64, 128, 16384, 0, 7, 7);
    // u2 = iwt(ic2) -> CAT1p interior ch16..31
    iwt_k<<<cdiv(T2M, 256), 256, 0, stream>>>(IC2, 64, 4, 7, 7,
                                              CAT1p + 16, 32, 258, I258, 1, T2M);
    // ic1 = lrelu(convd2(cat1)) -> IC1 flat [8,256,256,16]  (MFMA, N=16)
    conv_n16_k<<<dim3(P256 / 128), 256, 0, stream>>>(CAT1p, 258, I258, d2wb, d2b, IC1, 8, 8);
    // iw1 = lrelu(convd1(ic1)) -> IW1 flat [8,256,256,4]
    conv_direct_k<16, 4><<<cdiv(P256, 256), 256, 0, stream>>>(
        IC1, 16, d1w, d1b, IW1, 4, 256, 65536, 0, 8, 8, P256);
    // out = sigmoid(iwt(iw1))
    iwt_out_k<<<cdiv(P256, 256), 256, 0, stream>>>(IW1, outp, P256);
}

// Round 9
// 907.270 us; speedup vs baseline: 1.1426x; 1.1116x over previous
//
#include <hip/hip_runtime.h>
#include <cstddef>

// ---------------------------------------------------------------------------
// WaveletNet on MI355X — round 13: resubmit r12 (container infra failure, no
// data). B-deep pipeline: A = 4 bufs / 1 phase ahead; B = 6 bufs / 2 phases
// ahead; per-phase sync = {s_waitcnt vmcnt(4) lgkmcnt(0); s_barrier} leaves
// the newest 4 B-loads in flight. Barrier count unchanged vs r8. All LDS
// indices literal (6-phase period fully unrolled). 80KB LDS -> 2 blocks/CU.
// vmcnt ledger + buffer-reuse audit: see session notes (no hazards found).
// NT=2 path = r8 exactly.
// ---------------------------------------------------------------------------

typedef unsigned short u16;
typedef unsigned int u32;
typedef __bf16 bf16x8 __attribute__((ext_vector_type(8)));
typedef float floatx4 __attribute__((ext_vector_type(4)));
typedef u16 u16x4 __attribute__((ext_vector_type(4)));
typedef u16 u16x8 __attribute__((ext_vector_type(8)));

__device__ __forceinline__ float b2f(u16 h) {
    union { u32 u; float f; } x; x.u = ((u32)h) << 16; return x.f;
}
__device__ __forceinline__ u16 f2b(float f) {
    union { float f; u32 u; } x; x.f = f;
    return (u16)((x.u + 0x7FFFu + ((x.u >> 16) & 1u)) >> 16);
}
__device__ __forceinline__ float lrelu_f(float v) { return v > 0.f ? v : 0.2f * v; }

// async global->LDS, 16B per lane; LDS dest = wave-uniform base + lane*16
__device__ __forceinline__ void gld16(const u16* g, u16* l) {
    __builtin_amdgcn_global_load_lds(
        (const __attribute__((address_space(1))) u32*)(const void*)g,
        (__attribute__((address_space(3))) u32*)(void*)l, 16, 0, 0);
}

// phase-end sync: drain all but the newest 4 vmem loads (B two phases ahead)
#define WB4 asm volatile("s_waitcnt vmcnt(4) lgkmcnt(0)\ns_barrier" ::: "memory")
#define WB0 asm volatile("s_waitcnt vmcnt(0) lgkmcnt(0)\ns_barrier" ::: "memory")

// ---------------- MFMA implicit-GEMM conv3x3, padded NHWC ----------------
// A[m][k], k = tap*Cin+ci; input padded [B][H+2][W+2][Cin], border zero.
// Wb = [Cout][9*Cin]. BM=128, BN=NT*32, BK=32. 4 waves 2x2.
// LDS swizzle: 16B slot within 64B row stored at slot ^ ((row>>1)&3), applied
// via pre-swizzled GLOBAL source (linear LDS dest) + swizzled ds_read.
// NT=4: A 4 bufs (1 phase ahead), B 6 bufs (2 phases ahead), 2-chunk phases,
//       counted vmcnt(4) per phase. Requires nChunks % 12 == 0 (288/144/72).
// NT=2: r8 two-buffer loop (draining barrier per chunk).
template<int NT>
__global__ __launch_bounds__(256, 2)
void conv_mfma_k(const u16* __restrict__ in, int Cin, int iWp, int iImg,
                 const u16* __restrict__ wb, const float* __restrict__ bias,
                 const u16* __restrict__ skip, int sC, int sWp, int sImg, int spad,
                 u16* __restrict__ out, int Cst, int oWp, int oImg, int opad,
                 int logW, int logH)
{
    constexpr int BM = 128, BN = NT * 32;
    constexpr int ASZ = BM * 32;          // u16 per A buffer (4096 = 8 KB)
    constexpr int BSZ = BN * 32;
    constexpr int ANB = (NT == 4) ? 4 : 2;
    constexpr int BNB = (NT == 4) ? 6 : 2;
    __shared__ u16 At[ANB * ASZ];         // 32 KB (NT=4) / 16 KB (NT=2)
    __shared__ u16 Bt[BNB * BSZ];         // 48 KB (NT=4) /  8 KB (NT=2)

    const int tid = threadIdx.x;
    const int wid = tid >> 6, lane = tid & 63;
    const int W = 1 << logW, H = 1 << logH;
    const int mBase = blockIdx.x * BM;
    const int nBase = blockIdx.y * BN;
    const int K = 9 * Cin;
    const int kg = lane & 3;
    const int rr = lane >> 2;
    const int kgs = kg ^ ((rr >> 1) & 3);

    // per-lane loop-invariant global base pointers (tap (-1,-1) == padded (py,px))
    const u16 *gA0, *gA1, *gB0, *gB1 = nullptr;
    {
        int m0 = mBase + wid * 32 + rr;
        int px0 = m0 & (W - 1), py0 = (m0 >> logW) & (H - 1), pb0 = m0 >> (logW + logH);
        gA0 = in + ((size_t)pb0 * iImg + (size_t)py0 * iWp + px0) * Cin + kgs * 8;
        int m1 = m0 + 16;
        int px1 = m1 & (W - 1), py1 = (m1 >> logW) & (H - 1), pb1 = m1 >> (logW + logH);
        gA1 = in + ((size_t)pb1 * iImg + (size_t)py1 * iWp + px1) * Cin + kgs * 8;
    }
    if constexpr (NT == 4) {
        gB0 = wb + (size_t)(nBase + wid * 32 + rr) * K + kgs * 8;
        gB1 = wb + (size_t)(nBase + wid * 32 + 16 + rr) * K + kgs * 8;
    } else {
        gB0 = wb + (size_t)(nBase + wid * 16 + rr) * K + kgs * 8;
    }
    u16* lA0 = &At[wid * 1024];
    u16* lA1 = &At[wid * 1024 + 512];
    u16* lB0 = (NT == 4) ? &Bt[wid * 1024] : &Bt[wid * 512];
    u16* lB1 = (NT == 4) ? &Bt[wid * 1024 + 512] : nullptr;

    const int wm = wid >> 1, wn = wid & 1;
    const int fm = lane & 15;
    const int fk = ((lane >> 4) * 8) ^ (((fm >> 1) & 3) << 3);

    floatx4 acc[4][NT] = {};

    const int nChunks = K / 32;
    const size_t rowStep = (size_t)(iWp - 2) * Cin;
    int cbn = 0, tap = 0;

    auto stageA = [&](int buf) {
        gld16(gA0, lA0 + buf * ASZ);
        gld16(gA1, lA1 + buf * ASZ);
        size_t dA = 32;
        cbn += 32;
        if (cbn == Cin) { cbn = 0; ++tap; dA = ((tap % 3 == 0) ? rowStep : (size_t)Cin) - (size_t)(Cin - 32); }
        gA0 += dA; gA1 += dA;
    };

    auto stageB = [&](int buf) {
        gld16(gB0, lB0 + buf * BSZ);
        if constexpr (NT == 4) gld16(gB1, lB1 + buf * BSZ);
        gB0 += 32;
        if constexpr (NT == 4) gB1 += 32;
    };

    auto compute = [&](int ab, int bb) {
        const u16* Ab = &At[ab * ASZ];
        const u16* Bb = &Bt[bb * BSZ];
        bf16x8 af[4], bfr[NT];
#pragma unroll
        for (int mt = 0; mt < 4; ++mt)
            af[mt] = *(const bf16x8*)&Ab[(wm * 64 + mt * 16 + fm) * 32 + fk];
#pragma unroll
        for (int nt = 0; nt < NT; ++nt)
            bfr[nt] = *(const bf16x8*)&Bb[(wn * (NT * 16) + nt * 16 + fm) * 32 + fk];
        __builtin_amdgcn_s_setprio(1);
#pragma unroll
        for (int mt = 0; mt < 4; ++mt)
#pragma unroll
            for (int nt = 0; nt < NT; ++nt)
                acc[mt][nt] = __builtin_amdgcn_mfma_f32_16x16x32_bf16(af[mt], bfr[nt], acc[mt][nt], 0, 0, 0);
        __builtin_amdgcn_s_setprio(0);
    };

    if constexpr (NT == 4) {
        // 6-phase (12-chunk) buffer period, fully unrolled. Per phase: issue
        // A(p+1) then B(p+2); compute phase p; WB4 leaves B(p+2) in flight.
        // Prologue: A chunks 0,1; B chunks 0..3; drain all but B(2,3).
        stageA(0); stageA(1);
        stageB(0); stageB(1); stageB(2); stageB(3);
        WB4;
        const int nMac = nChunks / 12;
        for (int it = 0; it < nMac - 1; ++it) {
            stageA(2); stageA(3); stageB(4); stageB(5); compute(0, 0); compute(1, 1); WB4;
            stageA(0); stageA(1); stageB(0); stageB(1); compute(2, 2); compute(3, 3); WB4;
            stageA(2); stageA(3); stageB(2); stageB(3); compute(0, 4); compute(1, 5); WB4;
            stageA(0); stageA(1); stageB(4); stageB(5); compute(2, 0); compute(3, 1); WB4;
            stageA(2); stageA(3); stageB(0); stageB(1); compute(0, 2); compute(1, 3); WB4;
            stageA(0); stageA(1); stageB(2); stageB(3); compute(2, 4); compute(3, 5); WB4;
        }
        // final macro-iter (last 12 chunks)
        stageA(2); stageA(3); stageB(4); stageB(5); compute(0, 0); compute(1, 1); WB4;
        stageA(0); stageA(1); stageB(0); stageB(1); compute(2, 2); compute(3, 3); WB4;
        stageA(2); stageA(3); stageB(2); stageB(3); compute(0, 4); compute(1, 5); WB4;
        stageA(0); stageA(1); stageB(4); stageB(5); compute(2, 0); compute(3, 1); WB4;
        stageA(2); stageA(3);                       compute(0, 2); compute(1, 3); WB0;
        compute(2, 4); compute(3, 5);
    } else {
        // r8 two-buffer loop: one draining barrier per chunk (nChunks 18/36)
        stageA(0); stageB(0);
        __syncthreads();
        for (int kc = 0; kc < nChunks; kc += 2) {
            stageA(1); stageB(1);
            compute(0, 0);
            __syncthreads();
            if (kc + 2 < nChunks) { stageA(0); stageB(0); }
            compute(1, 1);
            __syncthreads();
        }
    }

    // epilogue: bias (+skip) + lrelu -> bf16 NHWC (padded or flat out)
    const int rq = (lane >> 4) * 4;
#pragma unroll
    for (int mt = 0; mt < 4; ++mt) {
        const int mrow = mBase + wm * 64 + mt * 16 + rq;
#pragma unroll
        for (int r = 0; r < 4; ++r) {
            int m2 = mrow + r;
            int px = m2 & (W - 1), py = (m2 >> logW) & (H - 1), pb2 = m2 >> (logW + logH);
            size_t ob = ((size_t)pb2 * oImg + (size_t)(py + opad) * oWp + (px + opad)) * Cst;
            size_t sb = 0;
            if (skip) sb = ((size_t)pb2 * sImg + (size_t)(py + spad) * sWp + (px + spad)) * sC;
#pragma unroll
            for (int nt = 0; nt < NT; ++nt) {
                int n = nBase + wn * (NT * 16) + nt * 16 + fm;
                float v = acc[mt][nt][r] + bias[n];
                if (skip) v += b2f(skip[sb + n]);
                v = lrelu_f(v);
                out[ob + n] = f2b(v);
            }
        }
    }
}

// ---------------- MFMA conv3x3, Cin=32 -> Cout=16 (convd2), padded in, flat out ----
__global__ __launch_bounds__(256)
void conv_n16_k(const u16* __restrict__ in, int iWp, int iImg,
                const u16* __restrict__ wb, const float* __restrict__ bias,
                u16* __restrict__ out, int logW, int logH)
{
    __shared__ u16 At[128 * 32];    // 8 KB
    __shared__ u16 Bt[16 * 32];     // 1 KB
    const int tid = threadIdx.x;
    const int wid = tid >> 6, lane = tid & 63;
    const int W = 1 << logW, H = 1 << logH;
    const int mBase = blockIdx.x * 128;
    const int kg = lane & 3, rr = lane >> 2;
    const int kgs = kg ^ ((rr >> 1) & 3);

    const u16 *gA0, *gA1;
    {
        int m0 = mBase + wid * 32 + rr;
        int px0 = m0 & (W - 1), py0 = (m0 >> logW) & (H - 1), pb0 = m0 >> (logW + logH);
        gA0 = in + ((size_t)pb0 * iImg + (size_t)py0 * iWp + px0) * 32 + kgs * 8;
        int m1 = m0 + 16;
        int px1 = m1 & (W - 1), py1 = (m1 >> logW) & (H - 1), pb1 = m1 >> (logW + logH);
        gA1 = in + ((size_t)pb1 * iImg + (size_t)py1 * iWp + px1) * 32 + kgs * 8;
    }
    const u16* gB = wb + (size_t)rr * 288 + kgs * 8;   // 16 rows (rr<16 used)
    u16* lA0 = &At[wid * 1024];
    u16* lA1 = &At[wid * 1024 + 512];

    const int fm = lane & 15;
    const int fk = ((lane >> 4) * 8) ^ (((fm >> 1) & 3) << 3);
    floatx4 acc[2] = {};
    const size_t rowStep = (size_t)(iWp - 2) * 32;

    for (int tap = 0; tap < 9; ++tap) {
        gld16(gA0, lA0);
        gld16(gA1, lA1);
        if (wid == 0) gld16(gB, &Bt[0]);
        __syncthreads();
        bf16x8 bf = *(const bf16x8*)&Bt[fm * 32 + fk];
#pragma unroll
        for (int mt = 0; mt < 2; ++mt) {
            bf16x8 af = *(const bf16x8*)&At[(wid * 32 + mt * 16 + fm) * 32 + fk];
            acc[mt] = __builtin_amdgcn_mfma_f32_16x16x32_bf16(af, bf, acc[mt], 0, 0, 0);
        }
        __syncthreads();
        size_t dA = (tap % 3 == 2) ? rowStep : (size_t)32;
        gA0 += dA; gA1 += dA; gB += 32;
    }

    const int rq = (lane >> 4) * 4;
    const float bn = bias[fm];
#pragma unroll
    for (int mt = 0; mt < 2; ++mt) {
#pragma unroll
        for (int r = 0; r < 4; ++r) {
            int m2 = mBase + wid * 32 + mt * 16 + rq + r;
            out[(size_t)m2 * 16 + fm] = f2b(lrelu_f(acc[mt][r] + bn));
        }
    }
}

// ---------------- direct NHWC conv3x3 (small channels), fp32 weights ----------------
template<int CIN, int COUT>
__global__ __launch_bounds__(256)
void conv_direct_k(const u16* __restrict__ in, int Sin,
                   const float* __restrict__ w, const float* __restrict__ bias,
                   u16* __restrict__ out, int Sout, int oWp, int oImg, int opad,
                   int logW, int logH, int total)
{
    int m = blockIdx.x * 256 + threadIdx.x;
    if (m >= total) return;
    const int W = 1 << logW, H = 1 << logH;
    const int px = m & (W - 1);
    const int py = (m >> logW) & (H - 1);
    const int pb = m >> (logW + logH);
    float acc[COUT];
#pragma unroll
    for (int o = 0; o < COUT; ++o) acc[o] = bias[o];
    for (int tap = 0; tap < 9; ++tap) {
        int dy = tap / 3 - 1, dx = tap % 3 - 1;
        int iy = py + dy, ix = px + dx;
        if ((unsigned)iy >= (unsigned)H || (unsigned)ix >= (unsigned)W) continue;
        const u16* p = in + (size_t)((((pb << logH) + iy) << logW) + ix) * Sin;
        if constexpr (CIN == 4) {
            u16x4 v = *(const u16x4*)p;
#pragma unroll
            for (int ci = 0; ci < 4; ++ci) {
                float f = b2f(v[ci]);
#pragma unroll
                for (int o = 0; o < COUT; ++o) acc[o] += f * w[(o * CIN + ci) * 9 + tap];
            }
        } else {
#pragma unroll
            for (int c8 = 0; c8 < CIN / 8; ++c8) {
                u16x8 v = *(const u16x8*)(p + c8 * 8);
#pragma unroll
                for (int j = 0; j < 8; ++j) {
                    int ci = c8 * 8 + j;
                    float f = b2f(v[j]);
#pragma unroll
                    for (int o = 0; o < COUT; ++o) acc[o] += f * w[(o * CIN + ci) * 9 + tap];
                }
            }
        }
    }
    size_t ob = ((size_t)pb * oImg + (size_t)(py + opad) * oWp + (px + opad)) * Sout;
#pragma unroll
    for (int o = 0; o < COUT; ++o)
        out[ob + o] = f2b(lrelu_f(acc[o]));
}

// ---------------- Haar wt / iwt, geometry-parametrized NHWC ----------------
__global__ __launch_bounds__(256)
void wt_in_k(const float* __restrict__ x, u16* __restrict__ out, int total)
{
    int idx = blockIdx.x * 256 + threadIdx.x;   // (b,h,w) of 8x256x256
    if (idx >= total) return;
    int wq = idx & 255, t = idx >> 8;
    int hq = t & 255, b = t >> 8;
    const float* p = x + ((size_t)b * 512 + 2 * hq) * 512 + 2 * wq;
    float a = p[0], bv = p[1], cv = p[512], d = p[513];
    u16x4 o = { f2b(0.25f * (a + bv + cv + d)),
                f2b(0.25f * (a + bv - cv - d) + 0.5f),
                f2b(0.25f * (a - bv + cv - d) + 0.5f),
                f2b(0.25f * (a - bv - cv + d) + 0.5f) };
    *(u16x4*)&out[(size_t)idx * 4] = o;
}

// in: maybe-padded NHWC [Sin]; out: maybe-padded NHWC [Sout], channels 4c+band
__global__ __launch_bounds__(256)
void wt_k(const u16* __restrict__ in, int Sin, int iWp, int iImg, int ipad,
          u16* __restrict__ out, int Sout, int oWp, int oImg, int opad,
          int logC, int logWo, int logHo, int total)
{
    int idx = blockIdx.x * 256 + threadIdx.x;
    if (idx >= total) return;
    const int C = 1 << logC, Wo = 1 << logWo, Ho = 1 << logHo;
    int c = idx & (C - 1); int t = idx >> logC;
    int wq = t & (Wo - 1); t >>= logWo;
    int hq = t & (Ho - 1); int b = t >> logHo;
    size_t p00 = ((size_t)b * iImg + (size_t)(2 * hq + ipad) * iWp + (2 * wq + ipad)) * Sin + c;
    float a  = b2f(in[p00]);
    float bv = b2f(in[p00 + Sin]);
    float cv = b2f(in[p00 + (size_t)iWp * Sin]);
    float d  = b2f(in[p00 + (size_t)iWp * Sin + Sin]);
    u16x4 o = { f2b(0.25f * (a + bv + cv + d)),
                f2b(0.25f * (a + bv - cv - d) + 0.5f),
                f2b(0.25f * (a - bv + cv - d) + 0.5f),
                f2b(0.25f * (a - bv - cv + d) + 0.5f) };
    *(u16x4*)&out[((size_t)b * oImg + (size_t)(hq + opad) * oWp + (wq + opad)) * Sout + 4 * c] = o;
}

// in: flat NHWC (unpadded), channels 4c+band; out: maybe-padded NHWC
__global__ __launch_bounds__(256)
void iwt_k(const u16* __restrict__ in, int Sin, int logC, int logW, int logH,
           u16* __restrict__ out, int Sout, int oWp, int oImg, int opad, int total)
{
    int idx = blockIdx.x * 256 + threadIdx.x;
    if (idx >= total) return;
    const int C = 1 << logC, W = 1 << logW;
    int c = idx & (C - 1); int t = idx >> logC;
    int wq = t & (W - 1); t >>= logW;
    int hq = t & ((1 << logH) - 1); int b = t >> logH;
    u16x4 v = *(const u16x4*)&in[(size_t)((((b << logH) + hq) << logW) + wq) * Sin + 4 * c];
    float y0 = b2f(v[0]);
    float y1 = 2.f * b2f(v[1]) - 1.f;
    float y2 = 2.f * b2f(v[2]) - 1.f;
    float y3 = 2.f * b2f(v[3]) - 1.f;
    float x00 = y0 + 0.5f * ( y1 + y2 + y3);
    float x01 = y0 + 0.5f * ( y1 - y2 - y3);
    float x10 = y0 + 0.5f * (-y1 + y2 - y3);
    float x11 = y0 + 0.5f * (-y1 - y2 + y3);
    size_t q = ((size_t)b * oImg + (size_t)(2 * hq + opad) * oWp + (2 * wq + opad)) * Sout + c;
    out[q] = f2b(x00);
    out[q + Sout] = f2b(x01);
    out[q + (size_t)oWp * Sout] = f2b(x10);
    out[q + (size_t)oWp * Sout + Sout] = f2b(x11);
}

__global__ __launch_bounds__(256)
void iwt_out_k(const u16* __restrict__ in, float* __restrict__ out, int total)
{
    int idx = blockIdx.x * 256 + threadIdx.x;   // (b,h,w) of 8x256x256
    if (idx >= total) return;
    int wq = idx & 255, t = idx >> 8;
    int hq = t & 255, b = t >> 8;
    u16x4 v = *(const u16x4*)&in[(size_t)idx * 4];
    float y0 = b2f(v[0]);
    float y1 = 2.f * b2f(v[1]) - 1.f;
    float y2 = 2.f * b2f(v[2]) - 1.f;
    float y3 = 2.f * b2f(v[3]) - 1.f;
    float x00 = y0 + 0.5f * ( y1 + y2 + y3);
    float x01 = y0 + 0.5f * ( y1 - y2 - y3);
    float x10 = y0 + 0.5f * (-y1 + y2 - y3);
    float x11 = y0 + 0.5f * (-y1 - y2 + y3);
    float* q = out + ((size_t)b * 512 + 2 * hq) * 512 + 2 * wq;
    q[0]   = 1.f / (1.f + __expf(-x00));
    q[1]   = 1.f / (1.f + __expf(-x01));
    q[512] = 1.f / (1.f + __expf(-x10));
    q[513] = 1.f / (1.f + __expf(-x11));
}

// ---------------- weight prep: [O][I][3][3] fp32 -> [O][tap][I] bf16 ----------------
__global__ __launch_bounds__(256)
void prep_w_k(const float* __restrict__ src, u16* __restrict__ dst, int logCIN, int total)
{
    int idx = blockIdx.x * 256 + threadIdx.x;
    if (idx >= total) return;
    const int CIN = 1 << logCIN;
    int ci = idx & (CIN - 1);
    int q = idx >> logCIN;
    int tap = q % 9, o = q / 9;
    dst[idx] = f2b(src[((size_t)(o * CIN + ci)) * 9 + tap]);
}

// ---------------- zero the 1-pixel border of a padded NHWC buffer ----------------
__global__ __launch_bounds__(256)
void zb_k(u16* __restrict__ buf, int Wp, int Hp, int C, int total)
{
    int idx = blockIdx.x * 256 + threadIdx.x;
    if (idx >= total) return;
    int c8 = idx % (C / 8); int t = idx / (C / 8);
    int nbp = 2 * Wp + 2 * (Hp - 2);
    int p = t % nbp; int b = t / nbp;
    int y, x;
    if (p < Wp) { y = 0; x = p; }
    else if (p < 2 * Wp) { y = Hp - 1; x = p - Wp; }
    else { int q = p - 2 * Wp; y = 1 + (q >> 1); x = (q & 1) ? Wp - 1 : 0; }
    u16x8 z = {0, 0, 0, 0, 0, 0, 0, 0};
    *(u16x8*)&buf[((size_t)b * Hp * Wp + (size_t)y * Wp + x) * C + c8 * 8] = z;
}

// ---------------------------------------------------------------------------
extern "C" void kernel_launch(void* const* d_in, const int* in_sizes, int n_in,
                              void* d_out, int out_size, void* d_ws, size_t ws_size,
                              hipStream_t stream)
{
    const float* x   = (const float*)d_in[0];
    const float* c1w = (const float*)d_in[1];  const float* c1b = (const float*)d_in[2];
    const float* c2w = (const float*)d_in[3];  const float* c2b = (const float*)d_in[4];
    const float* c3w = (const float*)d_in[5];  const float* c3b = (const float*)d_in[6];
    const float* c4w = (const float*)d_in[7];  const float* c4b = (const float*)d_in[8];
    const float* d1w = (const float*)d_in[9];  const float* d1b = (const float*)d_in[10];
    const float* d2w = (const float*)d_in[11]; const float* d2b = (const float*)d_in[12];
    const float* d3w = (const float*)d_in[13]; const float* d3b = (const float*)d_in[14];
    const float* d4w = (const float*)d_in[15]; const float* d4b = (const float*)d_in[16];

    const size_t MiB = 1u << 20;
    char* base = (char*)d_ws;
    // weights [0, 22 MiB)
    u16* c4wb = (u16*)base;                  // 9,437,184
    u16* c3wb = c4wb + 9437184;              //   589,824
    u16* d4wb = c3wb + 589824;               // 1,179,648
    u16* d3wb = d4wb + 1179648;              //    73,728
    u16* c2wb = d3wb + 73728;                //    36,864
    u16* d2wb = c2wb + 36864;                //     4,608
    // activations
    u16* CAT1p = (u16*)(base + 22  * MiB);   // [8,258,258,32]  padded: c1 | u2
    u16* CAT2p = (u16*)(base + 55  * MiB);   // [8,130,130,128] padded: c2 | u3
    u16* CAT3p = (u16*)(base + 88  * MiB);   // [8,66,66,512]   padded: c3 | u4
    u16* P1    = (u16*)(base + 123 * MiB);   // W2p -> W4p -> IC2
    u16* P2    = (u16*)(base + 142 * MiB);   // W3p -> C4p -> IC4 -> IC1
    u16* P3    = (u16*)(base + 161 * MiB);   // W1 -> C5p -> IC3 -> IW1
    float* outp = (float*)d_out;

    u16* W2p = P1; u16* W4p = P1; u16* IC2 = P1;
    u16* W3p = P2; u16* C4p = P2; u16* IC4 = P2; u16* IC1 = P2;
    u16* W1  = P3; u16* C5p = P3; u16* IC3 = P3; u16* IW1 = P3;

    auto cdiv = [](int a, int b) { return (a + b - 1) / b; };
    auto prep = [&](const float* s, u16* d, int logCIN, int total) {
        prep_w_k<<<cdiv(total, 256), 256, 0, stream>>>(s, d, logCIN, total);
    };
    auto zb = [&](u16* buf, int Wp, int Hp, int C) {
        int total = 8 * (2 * Wp + 2 * (Hp - 2)) * (C / 8);
        zb_k<<<cdiv(total, 256), 256, 0, stream>>>(buf, Wp, Hp, C, total);
    };
    auto mfma = [&](const u16* in, int Cin, int iWp, int iImg,
                    const u16* w, const float* bi,
                    const u16* skip, int sC, int sWp, int sImg, int spad,
                    int Cout, u16* out, int Cst, int oWp, int oImg, int opad,
                    int logW, int logH) {
        int M = 8 << (logW + logH);
        if (Cout % 128 == 0) {
            dim3 g(M / 128, Cout / 128);
            conv_mfma_k<4><<<g, 256, 0, stream>>>(in, Cin, iWp, iImg, w, bi,
                                                  skip, sC, sWp, sImg, spad,
                                                  out, Cst, oWp, oImg, opad, logW, logH);
        } else {
            dim3 g(M / 128, Cout / 64);
            conv_mfma_k<2><<<g, 256, 0, stream>>>(in, Cin, iWp, iImg, w, bi,
                                                  skip, sC, sWp, sImg, spad,
                                                  out, Cst, oWp, oImg, opad, logW, logH);
        }
    };

    // weight prep
    prep(c4w, c4wb, 10, 9437184);
    prep(c3w, c3wb, 8, 589824);
    prep(d4w, d4wb, 9, 1179648);
    prep(d3w, d3wb, 7, 73728);
    prep(c2w, c2wb, 6, 36864);
    prep(d2w, d2wb, 5, 4608);
    // borders whose slots have no earlier tenant
    zb(CAT1p, 258, 258, 32);
    zb(W2p, 130, 130, 64);
    zb(W3p, 66, 66, 256);
    zb(CAT2p, 130, 130, 128);
    zb(CAT3p, 66, 66, 512);

    const int P256 = 8 * 256 * 256;
    const int T2M = 2097152;   // 8*128*128*16 == 8*64*64*64 == 8*32*32*256
    const int I258 = 258 * 258;   // padded 256-image plane

    // w1 = wt(x) -> W1 (flat [8,256,256,4])
    wt_in_k<<<cdiv(P256, 256), 256, 0, stream>>>(x, W1, P256);
    // c1 -> CAT1p interior ch0..15 (direct, fp32 weights)
    conv_direct_k<4, 16><<<cdiv(P256, 256), 256, 0, stream>>>(
        W1, 4, c1w, c1b, CAT1p, 32, 258, I258, 1, 8, 8, P256);
    zb(C5p, 34, 34, 1024);                      // P3 free of W1 now
    // w2 = wt(c1) -> W2p padded [8,130,130,64]
    wt_k<<<cdiv(T2M, 256), 256, 0, stream>>>(CAT1p, 32, 258, I258, 1,
                                             W2p, 64, 130, 16900, 1, 4, 7, 7, T2M);
    // c2 -> CAT2p interior ch0..63
    mfma(W2p, 64, 130, 16900, c2wb, c2b, nullptr, 0, 0, 0, 0,
         64, CAT2p, 128, 130, 16900, 1, 7, 7);
    zb(W4p, 34, 34, 1024);                      // P1 free of W2p now
    // w3 = wt(c2) -> W3p padded [8,66,66,256]
    wt_k<<<cdiv(T2M, 256), 256, 0, stream>>>(CAT2p, 128, 130, 16900, 1,
                                             W3p, 256, 66, 4356, 1, 6, 6, 6, T2M);
    // c3 -> CAT3p interior ch0..255
    mfma(W3p, 256, 66, 4356, c3wb, c3b, nullptr, 0, 0, 0, 0,
         256, CAT3p, 512, 66, 4356, 1, 6, 6);
    zb(C4p, 34, 34, 1024);                      // P2 free of W3p now
    // w4 = wt(c3) -> W4p padded [8,34,34,1024]
    wt_k<<<cdiv(T2M, 256), 256, 0, stream>>>(CAT3p, 512, 66, 4356, 1,
                                             W4p, 1024, 34, 1156, 1, 8, 5, 5, T2M);
    // c4 -> C4p padded
    mfma(W4p, 1024, 34, 1156, c4wb, c4b, nullptr, 0, 0, 0, 0,
         1024, C4p, 1024, 34, 1156, 1, 5, 5);
    // c5 -> C5p padded
    mfma(C4p, 1024, 34, 1156, c4wb, c4b, nullptr, 0, 0, 0, 0,
         1024, C5p, 1024, 34, 1156, 1, 5, 5);
    // ic4 = lrelu(conv4(c5) + w4) -> IC4 flat [8,32,32,1024]
    mfma(C5p, 1024, 34, 1156, c4wb, c4b, W4p, 1024, 34, 1156, 1,
         1024, IC4, 1024, 32, 1024, 0, 5, 5);
    // u4 = iwt(ic4) -> CAT3p interior ch256..511
    iwt_k<<<cdiv(T2M, 256), 256, 0, stream>>>(IC4, 1024, 8, 5, 5,
                                              CAT3p + 256, 512, 66, 4356, 1, T2M);
    // ic3 = lrelu(convd4(cat3)) -> IC3 flat [8,64,64,256]
    mfma(CAT3p, 512, 66, 4356, d4wb, d4b, nullptr, 0, 0, 0, 0,
         256, IC3, 256, 64, 4096, 0, 6, 6);
    // u3 = iwt(ic3) -> CAT2p interior ch64..127
    iwt_k<<<cdiv(T2M, 256), 256, 0, stream>>>(IC3, 256, 6, 6, 6,
                                              CAT2p + 64, 128, 130, 16900, 1, T2M);
    // ic2 = lrelu(convd3(cat2)) -> IC2 flat [8,128,128,64]
    mfma(CAT2p, 128, 130, 16900, d3wb, d3b, nullptr, 0, 0, 0, 0,
         64, IC2, 64, 128, 16384, 0, 7, 7);
    // u2 = iwt(ic2) -> CAT1p interior ch16..31
    iwt_k<<<cdiv(T2M, 256), 256, 0, stream>>>(IC2, 64, 4, 7, 7,
                                              CAT1p + 16, 32, 258, I258, 1, T2M);
    // ic1 = lrelu(convd2(cat1)) -> IC1 flat [8,256,256,16]  (MFMA, N=16)
    conv_n16_k<<<dim3(P256 / 128), 256, 0, stream>>>(CAT1p, 258, I258, d2wb, d2b, IC1, 8, 8);
    // iw1 = lrelu(convd1(ic1)) -> IW1 flat [8,256,256,4]
    conv_direct_k<16, 4><<<cdiv(P256, 256), 256, 0, stream>>>(
        IC1, 16, d1w, d1b, IW1, 4, 256, 65536, 0, 8, 8, P256);
    // out = sigmoid(iwt(iw1))
    iwt_out_k<<<cdiv(P256, 256), 256, 0, stream>>>(IW1, outp, P256);
}